// Round 1
// baseline (1607.656 us; speedup 1.0000x reference)
//
#include <hip/hip_runtime.h>
#include <hip/hip_bf16.h>
#include <stdint.h>

// ---------------- problem constants ----------------
#define LL      3
#define NNODES  4000
#define NRELS   200
#define VV      20
#define EMB     128
#define HIDD    128
#define OUTD    100
#define WS_N    50000
#define WS_E    800000
#define BV      32
#define DECAYF  0.03f

// ---------------- GEMM (C[M,N] = A[M,K] * B[N,K]^T), bf16 MFMA ----------------
// SPLIT: split-bf16 (hi+lo) for ~f32 accuracy. RELU/BIAS: epilogue. ATOMIC: atomicAdd into C (split-K).
typedef __bf16 bf16x8 __attribute__((ext_vector_type(8)));
typedef float  f32x4  __attribute__((ext_vector_type(4)));

#define BM 128
#define BN 128
#define BKG 32
#define LSTR 40   // LDS row stride in bf16 elements (32 + 8 pad)

template<int SPLIT>
__device__ __forceinline__ void stage_tile(const float* __restrict__ G, int rows, int Kdim,
                                           int r0, int kb, int k1, __bf16* Sh, __bf16* Sl, int tid)
{
    const int sr  = tid >> 1;          // row 0..127
    const int skc = (tid & 1) * 16;    // k offset 0 or 16
    const int gr  = r0 + sr;
    const int gk  = kb + skc;
    float va[16];
    if (gr < rows && gk + 16 <= k1) {
        const float4* p4 = (const float4*)(G + (long)gr * Kdim + gk);
        #pragma unroll
        for (int q = 0; q < 4; q++) {
            float4 f = p4[q];
            va[4*q+0] = f.x; va[4*q+1] = f.y; va[4*q+2] = f.z; va[4*q+3] = f.w;
        }
    } else {
        #pragma unroll
        for (int j = 0; j < 16; j++) {
            int kk = gk + j;
            va[j] = (gr < rows && kk < k1) ? G[(long)gr * Kdim + kk] : 0.0f;
        }
    }
    bf16x8 h[2], lo[2];
    #pragma unroll
    for (int half = 0; half < 2; half++) {
        #pragma unroll
        for (int j = 0; j < 8; j++) {
            float v = va[half*8 + j];
            __bf16 hi = (__bf16)v;
            h[half][j]  = hi;
            lo[half][j] = (__bf16)(v - (float)hi);
        }
    }
    *(bf16x8*)&Sh[sr*LSTR + skc]     = h[0];
    *(bf16x8*)&Sh[sr*LSTR + skc + 8] = h[1];
    if (SPLIT) {
        *(bf16x8*)&Sl[sr*LSTR + skc]     = lo[0];
        *(bf16x8*)&Sl[sr*LSTR + skc + 8] = lo[1];
    }
}

template<int SPLIT, int RELU, int BIAS, int ATOMIC>
__global__ __launch_bounds__(256)
void gemm_bt(const float* __restrict__ Ag, const float* __restrict__ Bg,
             float* __restrict__ Cg, const float* __restrict__ bias,
             int M, int N, int K, long lBstride, long lCstride, int splitK)
{
    __shared__ __bf16 Ah[BM*LSTR];
    __shared__ __bf16 Bh[BN*LSTR];
    __shared__ __bf16 Alo[SPLIT ? BM*LSTR : 1];
    __shared__ __bf16 Blo[SPLIT ? BN*LSTR : 1];

    const int tid = threadIdx.x;
    const int bz  = blockIdx.z;
    const int l   = bz / splitK;
    const int kh  = bz % splitK;
    Bg += (long)l * lBstride;
    Cg += (long)l * lCstride;

    const int m0 = blockIdx.x * BM;
    const int n0 = blockIdx.y * BN;

    const int per = ((K + BKG*splitK - 1) / (BKG*splitK)) * BKG;
    const int k0  = kh * per;
    const int k1  = min(k0 + per, K);

    const int wave = tid >> 6;
    const int lane = tid & 63;
    const int wm = (wave & 1) * 64;
    const int wn = (wave >> 1) * 64;
    const int lr = lane & 15;
    const int kq = lane >> 4;

    f32x4 acc[4][4];
    #pragma unroll
    for (int i = 0; i < 4; i++)
        #pragma unroll
        for (int j = 0; j < 4; j++)
            acc[i][j] = (f32x4){0.f, 0.f, 0.f, 0.f};

    for (int kb = k0; kb < k1; kb += BKG) {
        stage_tile<SPLIT>(Ag, M, K, m0, kb, k1, Ah, Alo, tid);
        stage_tile<SPLIT>(Bg, N, K, n0, kb, k1, Bh, Blo, tid);
        __syncthreads();

        bf16x8 af[4], bfr[4];
        #pragma unroll
        for (int i = 0; i < 4; i++) {
            af[i]  = *(const bf16x8*)&Ah[(wm + i*16 + lr)*LSTR + kq*8];
            bfr[i] = *(const bf16x8*)&Bh[(wn + i*16 + lr)*LSTR + kq*8];
        }
        #pragma unroll
        for (int i = 0; i < 4; i++)
            #pragma unroll
            for (int j = 0; j < 4; j++)
                acc[i][j] = __builtin_amdgcn_mfma_f32_16x16x32_bf16(af[i], bfr[j], acc[i][j], 0, 0, 0);

        if (SPLIT) {
            bf16x8 al[4], bl[4];
            #pragma unroll
            for (int i = 0; i < 4; i++) {
                al[i] = *(const bf16x8*)&Alo[(wm + i*16 + lr)*LSTR + kq*8];
                bl[i] = *(const bf16x8*)&Blo[(wn + i*16 + lr)*LSTR + kq*8];
            }
            #pragma unroll
            for (int i = 0; i < 4; i++)
                #pragma unroll
                for (int j = 0; j < 4; j++) {
                    acc[i][j] = __builtin_amdgcn_mfma_f32_16x16x32_bf16(af[i], bl[j], acc[i][j], 0, 0, 0);
                    acc[i][j] = __builtin_amdgcn_mfma_f32_16x16x32_bf16(al[i], bfr[j], acc[i][j], 0, 0, 0);
                }
        }
        __syncthreads();
    }

    // epilogue: C/D layout col=lane&15, row=(lane>>4)*4+reg (m89/m91-verified)
    #pragma unroll
    for (int i = 0; i < 4; i++) {
        const int row_b = m0 + wm + i*16 + kq*4;
        #pragma unroll
        for (int j = 0; j < 4; j++) {
            const int col = n0 + wn + j*16 + lr;
            if (col < N) {
                #pragma unroll
                for (int r = 0; r < 4; r++) {
                    const int row = row_b + r;
                    if (row < M) {
                        float v = acc[i][j][r];
                        if (ATOMIC) {
                            atomicAdd(&Cg[(long)row*N + col], v);
                        } else {
                            if (BIAS) v += bias[col];
                            if (RELU) v = fmaxf(v, 0.0f);
                            Cg[(long)row*N + col] = v;
                        }
                    }
                }
            }
        }
    }
}

// ---------------- CSR build ----------------
__global__ void k_count(const int* __restrict__ dst, int* __restrict__ deg) {
    int e = blockIdx.x*256 + threadIdx.x;
    if (e < WS_E) atomicAdd(&deg[dst[e]], 1);
}

__global__ __launch_bounds__(1024) void k_scan(const int* __restrict__ deg, int* __restrict__ offs,
                                               int* __restrict__ cursor, int n) {
    __shared__ int part[1024];
    int t = threadIdx.x;
    int chunk = (n + 1023) / 1024;
    int s0 = t * chunk;
    int s1 = min(s0 + chunk, n);
    int s = 0;
    for (int i = s0; i < s1; i++) s += deg[i];
    part[t] = s; __syncthreads();
    for (int off = 1; off < 1024; off <<= 1) {
        int v = part[t];
        if (t >= off) v += part[t - off];
        __syncthreads();
        part[t] = v;
        __syncthreads();
    }
    int pre = (t == 0) ? 0 : part[t - 1];
    for (int i = s0; i < s1; i++) { offs[i] = pre; cursor[i] = pre; pre += deg[i]; }
    if (t == 1023) offs[n] = pre;
}

__global__ void k_fill(const int* __restrict__ dst, const int* __restrict__ src,
                       const int* __restrict__ rel, int* __restrict__ cursor,
                       int* __restrict__ ssrc, int* __restrict__ srel) {
    int e = blockIdx.x*256 + threadIdx.x;
    if (e < WS_E) {
        int d = dst[e];
        int p = atomicAdd(&cursor[d], 1);
        ssrc[p] = src[e];
        srel[p] = rel[e];
    }
}

// ---------------- small precompute kernels ----------------
__global__ __launch_bounds__(128) void k_relmsg(const float* __restrict__ Wrel, const float* __restrict__ wr_w,
                                                const float* __restrict__ wr_b, float* __restrict__ relmsg) {
    int l = blockIdx.x / NRELS;
    int r = blockIdx.x % NRELS;
    int o = threadIdx.x;
    float wv = Wrel[r*HIDD + o];
    __shared__ float red[128];
    red[o] = wv * wr_w[l*HIDD + o];
    __syncthreads();
    for (int s = 64; s > 0; s >>= 1) {
        if (o < s) red[o] += red[o + s];
        __syncthreads();
    }
    float wrel = red[0] + wr_b[l];
    relmsg[((long)l*NRELS + r)*HIDD + o] = wrel * wv;
}

__global__ void k_xinit(const float* __restrict__ Wnode, const int* __restrict__ nid, float* __restrict__ x) {
    int t = blockIdx.x*256 + threadIdx.x;
    if (t >= WS_N*32) return;
    int i = t >> 5;
    int d = t & 31;
    ((float4*)x)[i*32 + d] = ((const float4*)Wnode)[nid[i]*32 + d];
}

__global__ __launch_bounds__(256) void k_beta(const float* __restrict__ visit, const float* __restrict__ beta_w,
                                              const float* __restrict__ beta_b, float* __restrict__ beta) {
    int id = blockIdx.x;                 // l*640 + b*20 + v
    int l = id / (BV*VV);
    int rem = id % (BV*VV);
    int b = rem / VV;
    int v = rem % VV;
    const float* row = visit + ((long)b*VV + v) * NNODES;
    const float* wr  = beta_w + (long)l * NNODES;
    float s = 0.f;
    for (int n = threadIdx.x; n < NNODES; n += 256) s += row[n] * wr[n];
    __shared__ float red[256];
    red[threadIdx.x] = s; __syncthreads();
    for (int o = 128; o > 0; o >>= 1) {
        if (threadIdx.x < o) red[threadIdx.x] += red[threadIdx.x + o];
        __syncthreads();
    }
    if (threadIdx.x == 0) {
        float lam = __expf(DECAYF * (float)(VV - v));
        beta[id] = tanhf(red[0] + beta_b[l]) * lam;
    }
}

__global__ __launch_bounds__(256) void k_attnpool(const float* __restrict__ z, const float* __restrict__ beta,
                                                  float* __restrict__ attn) {
    int m = blockIdx.x*256 + threadIdx.x;
    int b = blockIdx.y;
    int l = blockIdx.z;
    if (m >= NNODES) return;
    const float* zb  = z + ((long)l*BV*VV + b*VV) * NNODES + m;
    const float* bet = beta + (l*BV + b) * VV;
    float zv[VV];
    float mx = -1e30f;
    #pragma unroll
    for (int v = 0; v < VV; v++) { zv[v] = zb[(long)v * NNODES]; mx = fmaxf(mx, zv[v]); }
    float s = 0.f, ws = 0.f;
    #pragma unroll
    for (int v = 0; v < VV; v++) {
        float e = __expf(zv[v] - mx);
        s += e;
        ws += e * bet[v];
    }
    attn[((long)l*BV + b) * NNODES + m] = ws / s;
}

__global__ void k_attn_node(const float* __restrict__ attn, const int* __restrict__ batch,
                            const int* __restrict__ nid, float* __restrict__ an) {
    int i = blockIdx.x*256 + threadIdx.x;
    int l = blockIdx.y;
    if (i >= WS_N) return;
    an[(long)l*WS_N + i] = attn[((long)l*BV + batch[i]) * NNODES + nid[i]];
}

// ---------------- message + aggregate (wave per dst node) ----------------
__global__ __launch_bounds__(256) void k_agg(const float* __restrict__ x, const float* __restrict__ an,
                                             const float* __restrict__ relmsg_l, const int* __restrict__ offs,
                                             const int* __restrict__ ssrc, const int* __restrict__ srel,
                                             float* __restrict__ outb) {
    int node = blockIdx.x*4 + (threadIdx.x >> 6);
    int lane = threadIdx.x & 63;
    if (node >= WS_N) return;
    int e0 = offs[node], e1 = offs[node + 1];
    const float2* x2  = (const float2*)x;
    const float2* rm2 = (const float2*)relmsg_l;
    float2 acc = {0.f, 0.f};
    int e = e0;
    for (; e + 1 < e1; e += 2) {
        int sa = ssrc[e],   ra = srel[e];
        int sb = ssrc[e+1], rb = srel[e+1];
        float aa = an[sa], ab = an[sb];
        float2 xa = x2[sa*64 + lane], va = rm2[ra*64 + lane];
        float2 xb = x2[sb*64 + lane], vb = rm2[rb*64 + lane];
        acc.x += fmaxf(xa.x*aa + va.x, 0.f) + fmaxf(xb.x*ab + vb.x, 0.f);
        acc.y += fmaxf(xa.y*aa + va.y, 0.f) + fmaxf(xb.y*ab + vb.y, 0.f);
    }
    if (e < e1) {
        int sa = ssrc[e], ra = srel[e];
        float aa = an[sa];
        float2 xa = x2[sa*64 + lane], va = rm2[ra*64 + lane];
        acc.x += fmaxf(xa.x*aa + va.x, 0.f);
        acc.y += fmaxf(xa.y*aa + va.y, 0.f);
    }
    float2 xo = x2[node*64 + lane];
    acc.x += xo.x; acc.y += xo.y;
    ((float2*)outb)[node*64 + lane] = acc;
}

// ---------------- final stage ----------------
__global__ void k_bstart(const int* __restrict__ batch, int* __restrict__ bstart) {
    int t = threadIdx.x;
    if (t > BV) return;
    int lo = 0, hi = WS_N;
    while (lo < hi) {
        int mid = (lo + hi) >> 1;
        if (batch[mid] < t) lo = mid + 1; else hi = mid;
    }
    bstart[t] = lo;
}

__global__ __launch_bounds__(128) void k_pool(const float* __restrict__ x, const int* __restrict__ bstart,
                                              float* __restrict__ xg) {
    int b = blockIdx.x;
    int d = threadIdx.x;
    int s0 = bstart[b], s1 = bstart[b + 1];
    float acc = 0.f;
    for (int i = s0; i < s1; i++) acc += x[(long)i*HIDD + d];
    int cnt = s1 - s0;
    xg[b*HIDD + d] = acc / (float)max(cnt, 1);
}

__global__ __launch_bounds__(128) void k_xnode(const float* __restrict__ ehr, const float* __restrict__ node_emb,
                                               const float* __restrict__ lin_w, const float* __restrict__ lin_b,
                                               float* __restrict__ xn) {
    int b = blockIdx.x;
    int d = threadIdx.x;
    float acc = 0.f, ssum = 0.f;
    for (int n = 0; n < NNODES; n++) {
        float e = ehr[b*NNODES + n];
        acc += e * node_emb[n*HIDD + d];
        ssum += e;
    }
    __shared__ float t1[128];
    t1[d] = acc / ssum;
    __syncthreads();
    float o2 = lin_b[d];
    for (int k2 = 0; k2 < HIDD; k2++) o2 += t1[k2] * lin_w[d*HIDD + k2];
    xn[b*HIDD + d] = o2;
}

__global__ __launch_bounds__(128) void k_mlp(const float* __restrict__ xg, const float* __restrict__ xn,
                                             const float* __restrict__ mlp_w, const float* __restrict__ mlp_b,
                                             float* __restrict__ out) {
    int b = blockIdx.x;
    int t = threadIdx.x;
    __shared__ float cat[2*HIDD];
    cat[t] = xg[b*HIDD + t];
    cat[HIDD + t] = xn[b*HIDD + t];
    __syncthreads();
    if (t < OUTD) {
        float acc = mlp_b[t];
        for (int j = 0; j < 2*HIDD; j++) acc += cat[j] * mlp_w[t*2*HIDD + j];
        out[b*OUTD + t] = acc;
    }
}

// ---------------- launcher ----------------
extern "C" void kernel_launch(void* const* d_in, const int* in_sizes, int n_in,
                              void* d_out, int out_size, void* d_ws, size_t ws_size,
                              hipStream_t stream)
{
    const float* node_emb = (const float*)d_in[0];
    const float* rel_emb  = (const float*)d_in[1];
    const float* lin_w    = (const float*)d_in[2];
    const float* lin_b    = (const float*)d_in[3];
    const float* alpha_w  = (const float*)d_in[4];
    // d_in[5] alpha_b: shift-invariant under softmax over v -> unused
    const float* beta_w   = (const float*)d_in[6];
    const float* beta_b   = (const float*)d_in[7];
    const float* wr_w     = (const float*)d_in[8];
    const float* wr_b     = (const float*)d_in[9];
    const float* conv_w   = (const float*)d_in[10];
    const float* conv_b   = (const float*)d_in[11];
    const float* mlp_w    = (const float*)d_in[12];
    const float* mlp_b    = (const float*)d_in[13];
    const float* visit    = (const float*)d_in[14];
    const float* ehr      = (const float*)d_in[15];
    const int* node_ids   = (const int*)d_in[16];
    const int* rel_ids    = (const int*)d_in[17];
    const int* ei         = (const int*)d_in[18];
    const int* batch      = (const int*)d_in[19];
    const int* esrc = ei;
    const int* edst = ei + WS_E;
    float* out = (float*)d_out;

    char* p = (char*)d_ws;
    auto take = [&](size_t bytes) -> char* {
        char* q = p;
        p += (bytes + 255) & ~(size_t)255;
        return q;
    };
    float* x      = (float*)take((size_t)WS_N*HIDD*4);             // 25.6 MB
    float* zbuf   = (float*)take((size_t)LL*BV*VV*NNODES*4);       // 30.7 MB (aggbuf aliases: z dead after attnpool)
    float* aggbuf = zbuf;
    float* attn   = (float*)take((size_t)LL*BV*NNODES*4);
    float* betab  = (float*)take((size_t)LL*BV*VV*4);
    float* attnnd = (float*)take((size_t)LL*WS_N*4);
    float* Wnode  = (float*)take((size_t)NNODES*HIDD*4);
    float* Wrel   = (float*)take((size_t)NRELS*HIDD*4);
    float* relmsg = (float*)take((size_t)LL*NRELS*HIDD*4);
    float* xg     = (float*)take((size_t)BV*HIDD*4);
    float* xn     = (float*)take((size_t)BV*HIDD*4);
    int* deg      = (int*)take((size_t)WS_N*4);
    int* offs     = (int*)take((size_t)(WS_N+1)*4);
    int* cursor   = (int*)take((size_t)WS_N*4);
    int* ssrc     = (int*)take((size_t)WS_E*4);
    int* srel     = (int*)take((size_t)WS_E*4);
    int* bstart   = (int*)take((size_t)(BV+1)*4);
    if ((size_t)(p - (char*)d_ws) > ws_size) return;  // ws too small: leave output poisoned (visible failure)

    (void)hipMemsetAsync(deg, 0, (size_t)WS_N*4, stream);
    (void)hipMemsetAsync(zbuf, 0, (size_t)LL*BV*VV*NNODES*4, stream);

    // CSR by dst (graph is layer-invariant)
    k_count<<<dim3((WS_E+255)/256), 256, 0, stream>>>(edst, deg);
    k_scan<<<1, 1024, 0, stream>>>(deg, offs, cursor, WS_N);
    k_fill<<<dim3((WS_E+255)/256), 256, 0, stream>>>(edst, esrc, rel_ids, cursor, ssrc, srel);

    // Wnode = node_emb @ lin_w^T + lin_b ; Wrel likewise (split-bf16 => ~f32 accuracy)
    gemm_bt<1,0,1,0><<<dim3((NNODES+BM-1)/BM, 1, 1), 256, 0, stream>>>(
        node_emb, lin_w, Wnode, lin_b, NNODES, HIDD, HIDD, 0, 0, 1);
    gemm_bt<1,0,1,0><<<dim3((NRELS+BM-1)/BM, 1, 1), 256, 0, stream>>>(
        rel_emb, lin_w, Wrel, lin_b, NRELS, HIDD, HIDD, 0, 0, 1);
    k_relmsg<<<dim3(LL*NRELS), 128, 0, stream>>>(Wrel, wr_w, wr_b, relmsg);
    k_xinit<<<dim3((WS_N*32+255)/256), 256, 0, stream>>>(Wnode, node_ids, x);
    k_beta<<<dim3(LL*BV*VV), 256, 0, stream>>>(visit, beta_w, beta_b, betab);

    // z[l, b*V+v, m] = visit2d @ alpha_w[l]^T  (all 3 layers fused, split-K=2, atomic epilogue)
    gemm_bt<0,0,0,1><<<dim3((BV*VV+BM-1)/BM, (NNODES+BN-1)/BN, LL*2), 256, 0, stream>>>(
        visit, alpha_w, zbuf, nullptr, BV*VV, NNODES, NNODES,
        (long)NNODES*NNODES, (long)BV*VV*NNODES, 2);

    k_attnpool<<<dim3((NNODES+255)/256, BV, LL), 256, 0, stream>>>(zbuf, betab, attn);
    k_attn_node<<<dim3((WS_N+255)/256, LL), 256, 0, stream>>>(attn, batch, node_ids, attnnd);

    for (int l = 0; l < LL; l++) {
        k_agg<<<dim3((WS_N+3)/4), 256, 0, stream>>>(
            x, attnnd + (size_t)l*WS_N, relmsg + (size_t)l*NRELS*HIDD, offs, ssrc, srel, aggbuf);
        gemm_bt<1,1,1,0><<<dim3((WS_N+BM-1)/BM, 1, 1), 256, 0, stream>>>(
            aggbuf, conv_w + (size_t)l*HIDD*HIDD, x, conv_b + (size_t)l*HIDD,
            WS_N, HIDD, HIDD, 0, 0, 1);
    }

    k_bstart<<<1, 64, 0, stream>>>(batch, bstart);
    k_pool<<<BV, 128, 0, stream>>>(x, bstart, xg);
    k_xnode<<<BV, 128, 0, stream>>>(ehr, node_emb, lin_w, lin_b, xn);
    k_mlp<<<BV, 128, 0, stream>>>(xg, xn, mlp_w, mlp_b, out);
}

// Round 2
// 1078.143 us; speedup vs baseline: 1.4911x; 1.4911x over previous
//
#include <hip/hip_runtime.h>
#include <hip/hip_bf16.h>
#include <stdint.h>

// ---------------- problem constants ----------------
#define LL      3
#define NNODES  4000
#define NRELS   200
#define VV      20
#define EMB     128
#define HIDD    128
#define OUTD    100
#define WS_N    50000
#define WS_E    800000
#define BV      32
#define DECAYF  0.03f

// ---------------- GEMM (C[M,N] = A[M,K] * B[N,K]^T), bf16 MFMA ----------------
typedef __bf16 bf16x8 __attribute__((ext_vector_type(8)));
typedef float  f32x4  __attribute__((ext_vector_type(4)));

#define BM 128
#define BN 128
#define BKG 32
#define LSTR 40   // LDS row stride in bf16 elements (32 + 8 pad)

template<int SPLIT>
__device__ __forceinline__ void stage_tile(const float* __restrict__ G, int rows, int Kdim,
                                           int r0, int kb, int k1, __bf16* Sh, __bf16* Sl, int tid)
{
    const int sr  = tid >> 1;          // row 0..127
    const int skc = (tid & 1) * 16;    // k offset 0 or 16
    const int gr  = r0 + sr;
    const int gk  = kb + skc;
    float va[16];
    if (gr < rows && gk + 16 <= k1) {
        const float4* p4 = (const float4*)(G + (long)gr * Kdim + gk);
        #pragma unroll
        for (int q = 0; q < 4; q++) {
            float4 f = p4[q];
            va[4*q+0] = f.x; va[4*q+1] = f.y; va[4*q+2] = f.z; va[4*q+3] = f.w;
        }
    } else {
        #pragma unroll
        for (int j = 0; j < 16; j++) {
            int kk = gk + j;
            va[j] = (gr < rows && kk < k1) ? G[(long)gr * Kdim + kk] : 0.0f;
        }
    }
    bf16x8 h[2], lo[2];
    #pragma unroll
    for (int half = 0; half < 2; half++) {
        #pragma unroll
        for (int j = 0; j < 8; j++) {
            float v = va[half*8 + j];
            __bf16 hi = (__bf16)v;
            h[half][j]  = hi;
            lo[half][j] = (__bf16)(v - (float)hi);
        }
    }
    *(bf16x8*)&Sh[sr*LSTR + skc]     = h[0];
    *(bf16x8*)&Sh[sr*LSTR + skc + 8] = h[1];
    if (SPLIT) {
        *(bf16x8*)&Sl[sr*LSTR + skc]     = lo[0];
        *(bf16x8*)&Sl[sr*LSTR + skc + 8] = lo[1];
    }
}

template<int SPLIT, int RELU, int BIAS, int ATOMIC>
__global__ __launch_bounds__(256)
void gemm_bt(const float* __restrict__ Ag, const float* __restrict__ Bg,
             float* __restrict__ Cg, const float* __restrict__ bias,
             int M, int N, int K, long lBstride, long lCstride, int splitK)
{
    __shared__ __bf16 Ah[BM*LSTR];
    __shared__ __bf16 Bh[BN*LSTR];
    __shared__ __bf16 Alo[SPLIT ? BM*LSTR : 1];
    __shared__ __bf16 Blo[SPLIT ? BN*LSTR : 1];

    const int tid = threadIdx.x;
    const int bz  = blockIdx.z;
    const int l   = bz / splitK;
    const int kh  = bz % splitK;
    Bg += (long)l * lBstride;
    Cg += (long)l * lCstride;

    const int m0 = blockIdx.x * BM;
    const int n0 = blockIdx.y * BN;

    const int per = ((K + BKG*splitK - 1) / (BKG*splitK)) * BKG;
    const int k0  = kh * per;
    const int k1  = min(k0 + per, K);

    const int wave = tid >> 6;
    const int lane = tid & 63;
    const int wm = (wave & 1) * 64;
    const int wn = (wave >> 1) * 64;
    const int lr = lane & 15;
    const int kq = lane >> 4;

    f32x4 acc[4][4];
    #pragma unroll
    for (int i = 0; i < 4; i++)
        #pragma unroll
        for (int j = 0; j < 4; j++)
            acc[i][j] = (f32x4){0.f, 0.f, 0.f, 0.f};

    for (int kb = k0; kb < k1; kb += BKG) {
        stage_tile<SPLIT>(Ag, M, K, m0, kb, k1, Ah, Alo, tid);
        stage_tile<SPLIT>(Bg, N, K, n0, kb, k1, Bh, Blo, tid);
        __syncthreads();

        bf16x8 af[4], bfr[4];
        #pragma unroll
        for (int i = 0; i < 4; i++) {
            af[i]  = *(const bf16x8*)&Ah[(wm + i*16 + lr)*LSTR + kq*8];
            bfr[i] = *(const bf16x8*)&Bh[(wn + i*16 + lr)*LSTR + kq*8];
        }
        #pragma unroll
        for (int i = 0; i < 4; i++)
            #pragma unroll
            for (int j = 0; j < 4; j++)
                acc[i][j] = __builtin_amdgcn_mfma_f32_16x16x32_bf16(af[i], bfr[j], acc[i][j], 0, 0, 0);

        if (SPLIT) {
            bf16x8 al[4], bl[4];
            #pragma unroll
            for (int i = 0; i < 4; i++) {
                al[i] = *(const bf16x8*)&Alo[(wm + i*16 + lr)*LSTR + kq*8];
                bl[i] = *(const bf16x8*)&Blo[(wn + i*16 + lr)*LSTR + kq*8];
            }
            #pragma unroll
            for (int i = 0; i < 4; i++)
                #pragma unroll
                for (int j = 0; j < 4; j++) {
                    acc[i][j] = __builtin_amdgcn_mfma_f32_16x16x32_bf16(af[i], bl[j], acc[i][j], 0, 0, 0);
                    acc[i][j] = __builtin_amdgcn_mfma_f32_16x16x32_bf16(al[i], bfr[j], acc[i][j], 0, 0, 0);
                }
        }
        __syncthreads();
    }

    // epilogue: C/D layout col=lane&15, row=(lane>>4)*4+reg (m89/m91-verified)
    #pragma unroll
    for (int i = 0; i < 4; i++) {
        const int row_b = m0 + wm + i*16 + kq*4;
        #pragma unroll
        for (int j = 0; j < 4; j++) {
            const int col = n0 + wn + j*16 + lr;
            if (col < N) {
                #pragma unroll
                for (int r = 0; r < 4; r++) {
                    const int row = row_b + r;
                    if (row < M) {
                        float v = acc[i][j][r];
                        if (ATOMIC) {
                            atomicAdd(&Cg[(long)row*N + col], v);
                        } else {
                            if (BIAS) v += bias[col];
                            if (RELU) v = fmaxf(v, 0.0f);
                            Cg[(long)row*N + col] = v;
                        }
                    }
                }
            }
        }
    }
}

// ---------------- CSR build ----------------
__global__ void k_count(const int* __restrict__ dst, int* __restrict__ deg) {
    int e = blockIdx.x*256 + threadIdx.x;
    if (e < WS_E) atomicAdd(&deg[dst[e]], 1);
}

__global__ __launch_bounds__(1024) void k_scan(const int* __restrict__ deg, int* __restrict__ offs,
                                               int* __restrict__ cursor, int n) {
    __shared__ int part[1024];
    int t = threadIdx.x;
    int chunk = (n + 1023) / 1024;
    int s0 = t * chunk;
    int s1 = min(s0 + chunk, n);
    int s = 0;
    for (int i = s0; i < s1; i++) s += deg[i];
    part[t] = s; __syncthreads();
    for (int off = 1; off < 1024; off <<= 1) {
        int v = part[t];
        if (t >= off) v += part[t - off];
        __syncthreads();
        part[t] = v;
        __syncthreads();
    }
    int pre = (t == 0) ? 0 : part[t - 1];
    for (int i = s0; i < s1; i++) { offs[i] = pre; cursor[i] = pre; pre += deg[i]; }
    if (t == 1023) offs[n] = pre;
}

__global__ void k_fill(const int* __restrict__ dst, const int* __restrict__ src,
                       const int* __restrict__ rel, int* __restrict__ cursor,
                       int* __restrict__ ssrc, int* __restrict__ srel) {
    int e = blockIdx.x*256 + threadIdx.x;
    if (e < WS_E) {
        int d = dst[e];
        int p = atomicAdd(&cursor[d], 1);
        ssrc[p] = src[e];
        srel[p] = rel[e];
    }
}

// ---------------- small precompute kernels ----------------
__global__ __launch_bounds__(128) void k_relmsg(const float* __restrict__ Wrel, const float* __restrict__ wr_w,
                                                const float* __restrict__ wr_b, float* __restrict__ relmsg) {
    int l = blockIdx.x / NRELS;
    int r = blockIdx.x % NRELS;
    int o = threadIdx.x;
    float wv = Wrel[r*HIDD + o];
    __shared__ float red[128];
    red[o] = wv * wr_w[l*HIDD + o];
    __syncthreads();
    for (int s = 64; s > 0; s >>= 1) {
        if (o < s) red[o] += red[o + s];
        __syncthreads();
    }
    float wrel = red[0] + wr_b[l];
    relmsg[((long)l*NRELS + r)*HIDD + o] = wrel * wv;
}

__global__ void k_xinit(const float* __restrict__ Wnode, const int* __restrict__ nid, float* __restrict__ x) {
    int t = blockIdx.x*256 + threadIdx.x;
    if (t >= WS_N*32) return;
    int i = t >> 5;
    int d = t & 31;
    ((float4*)x)[i*32 + d] = ((const float4*)Wnode)[nid[i]*32 + d];
}

__global__ __launch_bounds__(256) void k_beta(const float* __restrict__ visit, const float* __restrict__ beta_w,
                                              const float* __restrict__ beta_b, float* __restrict__ beta) {
    int id = blockIdx.x;                 // l*640 + b*20 + v
    int l = id / (BV*VV);
    int rem = id % (BV*VV);
    int b = rem / VV;
    int v = rem % VV;
    const float* row = visit + ((long)b*VV + v) * NNODES;
    const float* wr  = beta_w + (long)l * NNODES;
    float s = 0.f;
    for (int n = threadIdx.x; n < NNODES; n += 256) s += row[n] * wr[n];
    __shared__ float red[256];
    red[threadIdx.x] = s; __syncthreads();
    for (int o = 128; o > 0; o >>= 1) {
        if (threadIdx.x < o) red[threadIdx.x] += red[threadIdx.x + o];
        __syncthreads();
    }
    if (threadIdx.x == 0) {
        float lam = __expf(DECAYF * (float)(VV - v));
        beta[id] = tanhf(red[0] + beta_b[l]) * lam;
    }
}

__global__ __launch_bounds__(256) void k_attnpool(const float* __restrict__ z, const float* __restrict__ beta,
                                                  float* __restrict__ attn) {
    int m = blockIdx.x*256 + threadIdx.x;
    int b = blockIdx.y;
    int l = blockIdx.z;
    if (m >= NNODES) return;
    const float* zb  = z + ((long)l*BV*VV + b*VV) * NNODES + m;
    const float* bet = beta + (l*BV + b) * VV;
    float zv[VV];
    float mx = -1e30f;
    #pragma unroll
    for (int v = 0; v < VV; v++) { zv[v] = zb[(long)v * NNODES]; mx = fmaxf(mx, zv[v]); }
    float s = 0.f, ws = 0.f;
    #pragma unroll
    for (int v = 0; v < VV; v++) {
        float e = __expf(zv[v] - mx);
        s += e;
        ws += e * bet[v];
    }
    attn[((long)l*BV + b) * NNODES + m] = ws / s;
}

__global__ void k_attn_node(const float* __restrict__ attn, const int* __restrict__ batch,
                            const int* __restrict__ nid, float* __restrict__ an) {
    int i = blockIdx.x*256 + threadIdx.x;
    int l = blockIdx.y;
    if (i >= WS_N) return;
    an[(long)l*WS_N + i] = attn[((long)l*BV + batch[i]) * NNODES + nid[i]];
}

// ---------------- message + aggregate (wave per dst node) ----------------
__global__ __launch_bounds__(256) void k_agg(const float* __restrict__ x, const float* __restrict__ an,
                                             const float* __restrict__ relmsg_l, const int* __restrict__ offs,
                                             const int* __restrict__ ssrc, const int* __restrict__ srel,
                                             float* __restrict__ outb) {
    int node = blockIdx.x*4 + (threadIdx.x >> 6);
    int lane = threadIdx.x & 63;
    if (node >= WS_N) return;
    int e0 = offs[node], e1 = offs[node + 1];
    const float2* x2  = (const float2*)x;
    const float2* rm2 = (const float2*)relmsg_l;
    float2 acc = {0.f, 0.f};
    int e = e0;
    for (; e + 1 < e1; e += 2) {
        int sa = ssrc[e],   ra = srel[e];
        int sb = ssrc[e+1], rb = srel[e+1];
        float aa = an[sa], ab = an[sb];
        float2 xa = x2[sa*64 + lane], va = rm2[ra*64 + lane];
        float2 xb = x2[sb*64 + lane], vb = rm2[rb*64 + lane];
        acc.x += fmaxf(xa.x*aa + va.x, 0.f) + fmaxf(xb.x*ab + vb.x, 0.f);
        acc.y += fmaxf(xa.y*aa + va.y, 0.f) + fmaxf(xb.y*ab + vb.y, 0.f);
    }
    if (e < e1) {
        int sa = ssrc[e], ra = srel[e];
        float aa = an[sa];
        float2 xa = x2[sa*64 + lane], va = rm2[ra*64 + lane];
        acc.x += fmaxf(xa.x*aa + va.x, 0.f);
        acc.y += fmaxf(xa.y*aa + va.y, 0.f);
    }
    float2 xo = x2[node*64 + lane];
    acc.x += xo.x; acc.y += xo.y;
    ((float2*)outb)[node*64 + lane] = acc;
}

// ---------------- final stage ----------------
__global__ void k_bstart(const int* __restrict__ batch, int* __restrict__ bstart) {
    int t = threadIdx.x;
    if (t > BV) return;
    int lo = 0, hi = WS_N;
    while (lo < hi) {
        int mid = (lo + hi) >> 1;
        if (batch[mid] < t) lo = mid + 1; else hi = mid;
    }
    bstart[t] = lo;
}

// mean-pool phase 1: parallel partial sums over row chunks, batch-run flush via atomics.
// 391 blocks x 256 thr (2 row-lanes x 128 dims). xgsum must be zeroed.
__global__ __launch_bounds__(256) void k_pool_partial(const float* __restrict__ x,
                                                      const int* __restrict__ batch,
                                                      float* __restrict__ xgsum) {
    int r0 = blockIdx.x * 128;
    int d = threadIdx.x & 127;
    int rofs = threadIdx.x >> 7;       // 0 or 1
    int r1 = min(r0 + 128, WS_N);
    float acc = 0.f;
    int curb = -1;
    for (int i = r0 + rofs; i < r1; i += 2) {
        int b = batch[i];
        if (b != curb) {
            if (curb >= 0) atomicAdd(&xgsum[curb*HIDD + d], acc);
            acc = 0.f; curb = b;
        }
        acc += x[(long)i*HIDD + d];
    }
    if (curb >= 0) atomicAdd(&xgsum[curb*HIDD + d], acc);
}

__global__ __launch_bounds__(128) void k_pool_fin(const float* __restrict__ xgsum,
                                                  const int* __restrict__ bstart,
                                                  float* __restrict__ xg) {
    int b = blockIdx.x;
    int d = threadIdx.x;
    int cnt = bstart[b+1] - bstart[b];
    xg[b*HIDD + d] = xgsum[b*HIDD + d] / (float)max(cnt, 1);
}

// x_node phase 1: ehr @ node_emb partial sums + ehr row-sum, parallel over n-chunks.
// grid (16, BV), 128 thr; xnsum/esum must be zeroed.
__global__ __launch_bounds__(128) void k_ehrpool(const float* __restrict__ ehr,
                                                 const float* __restrict__ node_emb,
                                                 float* __restrict__ xnsum, float* __restrict__ esum) {
    int b = blockIdx.y;
    int c = blockIdx.x;
    int d = threadIdx.x;
    int n0 = c * (NNODES/16), n1 = n0 + (NNODES/16);
    float acc = 0.f;
    for (int n = n0; n < n1; n++) {
        acc += ehr[b*NNODES + n] * node_emb[(long)n*HIDD + d];
    }
    atomicAdd(&xnsum[b*HIDD + d], acc);
    float s = 0.f;
    for (int n = n0 + d; n < n1; n += 128) s += ehr[b*NNODES + n];
    __shared__ float red[128];
    red[d] = s; __syncthreads();
    for (int o = 64; o > 0; o >>= 1) {
        if (d < o) red[d] += red[d + o];
        __syncthreads();
    }
    if (d == 0) atomicAdd(&esum[b], red[0]);
}

__global__ __launch_bounds__(128) void k_xnode_fin(const float* __restrict__ xnsum,
                                                   const float* __restrict__ esum,
                                                   const float* __restrict__ lin_w,
                                                   const float* __restrict__ lin_b,
                                                   float* __restrict__ xn) {
    int b = blockIdx.x;
    int d = threadIdx.x;
    __shared__ float t1[128];
    t1[d] = xnsum[b*HIDD + d] / esum[b];
    __syncthreads();
    float o2 = lin_b[d];
    for (int k2 = 0; k2 < HIDD; k2++) o2 += t1[k2] * lin_w[d*HIDD + k2];
    xn[b*HIDD + d] = o2;
}

__global__ __launch_bounds__(128) void k_mlp(const float* __restrict__ xg, const float* __restrict__ xn,
                                             const float* __restrict__ mlp_w, const float* __restrict__ mlp_b,
                                             float* __restrict__ out) {
    int b = blockIdx.x;
    int t = threadIdx.x;
    __shared__ float cat[2*HIDD];
    cat[t] = xg[b*HIDD + t];
    cat[HIDD + t] = xn[b*HIDD + t];
    __syncthreads();
    if (t < OUTD) {
        float acc = mlp_b[t];
        for (int j = 0; j < 2*HIDD; j++) acc += cat[j] * mlp_w[t*2*HIDD + j];
        out[b*OUTD + t] = acc;
    }
}

// ---------------- launcher ----------------
extern "C" void kernel_launch(void* const* d_in, const int* in_sizes, int n_in,
                              void* d_out, int out_size, void* d_ws, size_t ws_size,
                              hipStream_t stream)
{
    const float* node_emb = (const float*)d_in[0];
    const float* rel_emb  = (const float*)d_in[1];
    const float* lin_w    = (const float*)d_in[2];
    const float* lin_b    = (const float*)d_in[3];
    const float* alpha_w  = (const float*)d_in[4];
    // d_in[5] alpha_b: shift-invariant under softmax over v -> unused
    const float* beta_w   = (const float*)d_in[6];
    const float* beta_b   = (const float*)d_in[7];
    const float* wr_w     = (const float*)d_in[8];
    const float* wr_b     = (const float*)d_in[9];
    const float* conv_w   = (const float*)d_in[10];
    const float* conv_b   = (const float*)d_in[11];
    const float* mlp_w    = (const float*)d_in[12];
    const float* mlp_b    = (const float*)d_in[13];
    const float* visit    = (const float*)d_in[14];
    const float* ehr      = (const float*)d_in[15];
    const int* node_ids   = (const int*)d_in[16];
    const int* rel_ids    = (const int*)d_in[17];
    const int* ei         = (const int*)d_in[18];
    const int* batch      = (const int*)d_in[19];
    const int* esrc = ei;
    const int* edst = ei + WS_E;
    float* out = (float*)d_out;

    char* p = (char*)d_ws;
    auto take = [&](size_t bytes) -> char* {
        char* q = p;
        p += (bytes + 255) & ~(size_t)255;
        return q;
    };
    float* x      = (float*)take((size_t)WS_N*HIDD*4);             // 25.6 MB
    float* zbuf   = (float*)take((size_t)LL*BV*VV*NNODES*4);       // 30.7 MB (aggbuf aliases: z dead after attnpool)
    float* aggbuf = zbuf;
    float* attn   = (float*)take((size_t)LL*BV*NNODES*4);
    float* betab  = (float*)take((size_t)LL*BV*VV*4);
    float* attnnd = (float*)take((size_t)LL*WS_N*4);
    float* Wnode  = (float*)take((size_t)NNODES*HIDD*4);
    float* Wrel   = (float*)take((size_t)NRELS*HIDD*4);
    float* relmsg = (float*)take((size_t)LL*NRELS*HIDD*4);
    // small accumulators zeroed with ONE memset: keep contiguous
    float* xgsum  = (float*)take((size_t)BV*HIDD*4);
    float* xnsum  = (float*)take((size_t)BV*HIDD*4);
    float* esum   = (float*)take((size_t)BV*4);
    size_t small_zero_bytes = (size_t)((char*)(esum + BV) - (char*)xgsum);
    float* xg     = (float*)take((size_t)BV*HIDD*4);
    float* xn     = (float*)take((size_t)BV*HIDD*4);
    int* deg      = (int*)take((size_t)WS_N*4);
    int* offs     = (int*)take((size_t)(WS_N+1)*4);
    int* cursor   = (int*)take((size_t)WS_N*4);
    int* ssrc     = (int*)take((size_t)WS_E*4);
    int* srel     = (int*)take((size_t)WS_E*4);
    int* bstart   = (int*)take((size_t)(BV+1)*4);
    if ((size_t)(p - (char*)d_ws) > ws_size) return;  // ws too small: leave output poisoned (visible failure)

    (void)hipMemsetAsync(deg, 0, (size_t)WS_N*4, stream);
    (void)hipMemsetAsync(zbuf, 0, (size_t)LL*BV*VV*NNODES*4, stream);
    (void)hipMemsetAsync(xgsum, 0, small_zero_bytes, stream);

    // CSR by dst (graph is layer-invariant)
    k_count<<<dim3((WS_E+255)/256), 256, 0, stream>>>(edst, deg);
    k_scan<<<1, 1024, 0, stream>>>(deg, offs, cursor, WS_N);
    k_fill<<<dim3((WS_E+255)/256), 256, 0, stream>>>(edst, esrc, rel_ids, cursor, ssrc, srel);

    // Wnode = node_emb @ lin_w^T + lin_b ; Wrel likewise (split-bf16 => ~f32 accuracy)
    gemm_bt<1,0,1,0><<<dim3((NNODES+BM-1)/BM, 1, 1), 256, 0, stream>>>(
        node_emb, lin_w, Wnode, lin_b, NNODES, HIDD, HIDD, 0, 0, 1);
    gemm_bt<1,0,1,0><<<dim3((NRELS+BM-1)/BM, 1, 1), 256, 0, stream>>>(
        rel_emb, lin_w, Wrel, lin_b, NRELS, HIDD, HIDD, 0, 0, 1);
    k_relmsg<<<dim3(LL*NRELS), 128, 0, stream>>>(Wrel, wr_w, wr_b, relmsg);
    k_xinit<<<dim3((WS_N*32+255)/256), 256, 0, stream>>>(Wnode, node_ids, x);
    k_beta<<<dim3(LL*BV*VV), 256, 0, stream>>>(visit, beta_w, beta_b, betab);

    // z[l, b*V+v, m] = visit2d @ alpha_w[l]^T  (all 3 layers fused, split-K=2, atomic epilogue)
    gemm_bt<0,0,0,1><<<dim3((BV*VV+BM-1)/BM, (NNODES+BN-1)/BN, LL*2), 256, 0, stream>>>(
        visit, alpha_w, zbuf, nullptr, BV*VV, NNODES, NNODES,
        (long)NNODES*NNODES, (long)BV*VV*NNODES, 2);

    k_attnpool<<<dim3((NNODES+255)/256, BV, LL), 256, 0, stream>>>(zbuf, betab, attn);
    k_attn_node<<<dim3((WS_N+255)/256, LL), 256, 0, stream>>>(attn, batch, node_ids, attnnd);

    for (int l = 0; l < LL; l++) {
        k_agg<<<dim3((WS_N+3)/4), 256, 0, stream>>>(
            x, attnnd + (size_t)l*WS_N, relmsg + (size_t)l*NRELS*HIDD, offs, ssrc, srel, aggbuf);
        gemm_bt<1,1,1,0><<<dim3((WS_N+BM-1)/BM, 1, 1), 256, 0, stream>>>(
            aggbuf, conv_w + (size_t)l*HIDD*HIDD, x, conv_b + (size_t)l*HIDD,
            WS_N, HIDD, HIDD, 0, 0, 1);
    }

    k_bstart<<<1, 64, 0, stream>>>(batch, bstart);
    k_pool_partial<<<dim3((WS_N+127)/128), 256, 0, stream>>>(x, batch, xgsum);
    k_pool_fin<<<BV, 128, 0, stream>>>(xgsum, bstart, xg);
    k_ehrpool<<<dim3(16, BV), 128, 0, stream>>>(ehr, node_emb, xnsum, esum);
    k_xnode_fin<<<BV, 128, 0, stream>>>(xnsum, esum, lin_w, lin_b, xn);
    k_mlp<<<BV, 128, 0, stream>>>(xg, xn, mlp_w, mlp_b, out);
}

// Round 3
// 1035.464 us; speedup vs baseline: 1.5526x; 1.0412x over previous
//
#include <hip/hip_runtime.h>
#include <hip/hip_bf16.h>
#include <stdint.h>

// ---------------- problem constants ----------------
#define LL      3
#define NNODES  4000
#define NRELS   200
#define VV      20
#define EMB     128
#define HIDD    128
#define OUTD    100
#define WS_N    50000
#define WS_E    800000
#define BV      32
#define DECAYF  0.03f

// ---------------- GEMM (C[M,N] = A[M,K] * B[N,K]^T), bf16 MFMA ----------------
typedef __bf16 bf16x8 __attribute__((ext_vector_type(8)));
typedef __bf16 bf16x4 __attribute__((ext_vector_type(4)));
typedef __bf16 bf16x2 __attribute__((ext_vector_type(2)));
typedef float  f32x4  __attribute__((ext_vector_type(4)));

#define BM 128
#define BN 128
#define BKG 32
#define LSTR 40   // LDS row stride in bf16 elements (32 + 8 pad)

template<int SPLIT>
__device__ __forceinline__ void stage_tile(const float* __restrict__ G, int rows, int Kdim,
                                           int r0, int kb, int k1, __bf16* Sh, __bf16* Sl, int tid)
{
    const int sr  = tid >> 1;          // row 0..127
    const int skc = (tid & 1) * 16;    // k offset 0 or 16
    const int gr  = r0 + sr;
    const int gk  = kb + skc;
    float va[16];
    if (gr < rows && gk + 16 <= k1) {
        const float4* p4 = (const float4*)(G + (long)gr * Kdim + gk);
        #pragma unroll
        for (int q = 0; q < 4; q++) {
            float4 f = p4[q];
            va[4*q+0] = f.x; va[4*q+1] = f.y; va[4*q+2] = f.z; va[4*q+3] = f.w;
        }
    } else {
        #pragma unroll
        for (int j = 0; j < 16; j++) {
            int kk = gk + j;
            va[j] = (gr < rows && kk < k1) ? G[(long)gr * Kdim + kk] : 0.0f;
        }
    }
    bf16x8 h[2], lo[2];
    #pragma unroll
    for (int half = 0; half < 2; half++) {
        #pragma unroll
        for (int j = 0; j < 8; j++) {
            float v = va[half*8 + j];
            __bf16 hi = (__bf16)v;
            h[half][j]  = hi;
            lo[half][j] = (__bf16)(v - (float)hi);
        }
    }
    *(bf16x8*)&Sh[sr*LSTR + skc]     = h[0];
    *(bf16x8*)&Sh[sr*LSTR + skc + 8] = h[1];
    if (SPLIT) {
        *(bf16x8*)&Sl[sr*LSTR + skc]     = lo[0];
        *(bf16x8*)&Sl[sr*LSTR + skc + 8] = lo[1];
    }
}

template<int SPLIT, int RELU, int BIAS, int WRITEB>
__global__ __launch_bounds__(256)
void gemm_bt(const float* __restrict__ Ag, const float* __restrict__ Bg,
             float* __restrict__ Cg, const float* __restrict__ bias,
             __bf16* __restrict__ Xb, int M, int N, int K)
{
    __shared__ __bf16 Ah[BM*LSTR];
    __shared__ __bf16 Bh[BN*LSTR];
    __shared__ __bf16 Alo[SPLIT ? BM*LSTR : 1];
    __shared__ __bf16 Blo[SPLIT ? BN*LSTR : 1];

    const int tid = threadIdx.x;
    const int m0 = blockIdx.x * BM;
    const int n0 = blockIdx.y * BN;

    const int wave = tid >> 6;
    const int lane = tid & 63;
    const int wm = (wave & 1) * 64;
    const int wn = (wave >> 1) * 64;
    const int lr = lane & 15;
    const int kq = lane >> 4;

    f32x4 acc[4][4];
    #pragma unroll
    for (int i = 0; i < 4; i++)
        #pragma unroll
        for (int j = 0; j < 4; j++)
            acc[i][j] = (f32x4){0.f, 0.f, 0.f, 0.f};

    for (int kb = 0; kb < K; kb += BKG) {
        stage_tile<SPLIT>(Ag, M, K, m0, kb, K, Ah, Alo, tid);
        stage_tile<SPLIT>(Bg, N, K, n0, kb, K, Bh, Blo, tid);
        __syncthreads();

        bf16x8 af[4], bfr[4];
        #pragma unroll
        for (int i = 0; i < 4; i++) {
            af[i]  = *(const bf16x8*)&Ah[(wm + i*16 + lr)*LSTR + kq*8];
            bfr[i] = *(const bf16x8*)&Bh[(wn + i*16 + lr)*LSTR + kq*8];
        }
        #pragma unroll
        for (int i = 0; i < 4; i++)
            #pragma unroll
            for (int j = 0; j < 4; j++)
                acc[i][j] = __builtin_amdgcn_mfma_f32_16x16x32_bf16(af[i], bfr[j], acc[i][j], 0, 0, 0);

        if (SPLIT) {
            bf16x8 al[4], bl[4];
            #pragma unroll
            for (int i = 0; i < 4; i++) {
                al[i] = *(const bf16x8*)&Alo[(wm + i*16 + lr)*LSTR + kq*8];
                bl[i] = *(const bf16x8*)&Blo[(wn + i*16 + lr)*LSTR + kq*8];
            }
            #pragma unroll
            for (int i = 0; i < 4; i++)
                #pragma unroll
                for (int j = 0; j < 4; j++) {
                    acc[i][j] = __builtin_amdgcn_mfma_f32_16x16x32_bf16(af[i], bl[j], acc[i][j], 0, 0, 0);
                    acc[i][j] = __builtin_amdgcn_mfma_f32_16x16x32_bf16(al[i], bfr[j], acc[i][j], 0, 0, 0);
                }
        }
        __syncthreads();
    }

    // epilogue: C/D layout col=lane&15, row=(lane>>4)*4+reg (m89/m91-verified)
    #pragma unroll
    for (int i = 0; i < 4; i++) {
        const int row_b = m0 + wm + i*16 + kq*4;
        #pragma unroll
        for (int j = 0; j < 4; j++) {
            const int col = n0 + wn + j*16 + lr;
            if (col < N) {
                #pragma unroll
                for (int r = 0; r < 4; r++) {
                    const int row = row_b + r;
                    if (row < M) {
                        float v = acc[i][j][r];
                        if (BIAS) v += bias[col];
                        if (RELU) v = fmaxf(v, 0.0f);
                        Cg[(long)row*N + col] = v;
                        if (WRITEB) Xb[(long)row*N + col] = (__bf16)v;
                    }
                }
            }
        }
    }
}

// ---------------- alpha GEMM: z[l,row,col] = visit[row,:] . alpha_w[l][col,:] ----------------
// 1-D grid of 480 blocks, XCD-grouped swizzle: assuming round-robin block->XCD (id%8),
// the 5 m-blocks sharing one alpha_w B-tile land on the SAME XCD so the 192 MB alpha_w
// stream is fetched from HBM once and re-read from that XCD's L2.
__global__ __launch_bounds__(256)
void gemm_alpha(const float* __restrict__ visit, const float* __restrict__ alpha_w,
                float* __restrict__ z)
{
    __shared__ __bf16 Ah[BM*LSTR];
    __shared__ __bf16 Bh[BN*LSTR];

    const int id   = blockIdx.x;      // 0..479
    const int xcd  = id & 7;
    const int slot = id >> 3;         // 0..59
    const int gix  = slot / 5;        // 0..11
    const int mi   = slot % 5;        // 0..4
    const int g    = xcd * 12 + gix;  // 0..95
    const int ni   = g & 31;          // 0..31
    const int l    = g >> 5;          // 0..2

    const float* Bg = alpha_w + (long)l * NNODES * NNODES;
    float*       Cg = z + (long)l * (BV*VV) * NNODES;
    const int m0 = mi * BM;
    const int n0 = ni * BN;

    const int tid = threadIdx.x;
    const int wave = tid >> 6;
    const int lane = tid & 63;
    const int wm = (wave & 1) * 64;
    const int wn = (wave >> 1) * 64;
    const int lr = lane & 15;
    const int kq = lane >> 4;

    f32x4 acc[4][4];
    #pragma unroll
    for (int i = 0; i < 4; i++)
        #pragma unroll
        for (int j = 0; j < 4; j++)
            acc[i][j] = (f32x4){0.f, 0.f, 0.f, 0.f};

    for (int kb = 0; kb < NNODES; kb += BKG) {
        stage_tile<0>(visit, BV*VV, NNODES, m0, kb, NNODES, Ah, nullptr, tid);
        stage_tile<0>(Bg, NNODES, NNODES, n0, kb, NNODES, Bh, nullptr, tid);
        __syncthreads();

        bf16x8 af[4], bfr[4];
        #pragma unroll
        for (int i = 0; i < 4; i++) {
            af[i]  = *(const bf16x8*)&Ah[(wm + i*16 + lr)*LSTR + kq*8];
            bfr[i] = *(const bf16x8*)&Bh[(wn + i*16 + lr)*LSTR + kq*8];
        }
        #pragma unroll
        for (int i = 0; i < 4; i++)
            #pragma unroll
            for (int j = 0; j < 4; j++)
                acc[i][j] = __builtin_amdgcn_mfma_f32_16x16x32_bf16(af[i], bfr[j], acc[i][j], 0, 0, 0);
        __syncthreads();
    }

    #pragma unroll
    for (int i = 0; i < 4; i++) {
        const int row_b = m0 + wm + i*16 + kq*4;   // rows < 640 always
        #pragma unroll
        for (int j = 0; j < 4; j++) {
            const int col = n0 + wn + j*16 + lr;
            if (col < NNODES) {
                #pragma unroll
                for (int r = 0; r < 4; r++)
                    Cg[(long)(row_b + r)*NNODES + col] = acc[i][j][r];
            }
        }
    }
}

// ---------------- CSR build ----------------
__global__ void k_count(const int* __restrict__ dst, int* __restrict__ deg) {
    int e = blockIdx.x*256 + threadIdx.x;
    if (e < WS_E) atomicAdd(&deg[dst[e]], 1);
}

__global__ __launch_bounds__(1024) void k_scan(const int* __restrict__ deg, int* __restrict__ offs,
                                               int* __restrict__ cursor, int n) {
    __shared__ int part[1024];
    int t = threadIdx.x;
    int chunk = (n + 1023) / 1024;
    int s0 = t * chunk;
    int s1 = min(s0 + chunk, n);
    int s = 0;
    for (int i = s0; i < s1; i++) s += deg[i];
    part[t] = s; __syncthreads();
    for (int off = 1; off < 1024; off <<= 1) {
        int v = part[t];
        if (t >= off) v += part[t - off];
        __syncthreads();
        part[t] = v;
        __syncthreads();
    }
    int pre = (t == 0) ? 0 : part[t - 1];
    for (int i = s0; i < s1; i++) { offs[i] = pre; cursor[i] = pre; pre += deg[i]; }
    if (t == 1023) offs[n] = pre;
}

__global__ void k_fill(const int* __restrict__ dst, const int* __restrict__ src,
                       const int* __restrict__ rel, int* __restrict__ cursor,
                       int* __restrict__ ssrc, int* __restrict__ srel) {
    int e = blockIdx.x*256 + threadIdx.x;
    if (e < WS_E) {
        int d = dst[e];
        int p = atomicAdd(&cursor[d], 1);
        ssrc[p] = src[e];
        srel[p] = rel[e];
    }
}

// ---------------- small precompute kernels ----------------
__global__ __launch_bounds__(128) void k_relmsg(const float* __restrict__ Wrel, const float* __restrict__ wr_w,
                                                const float* __restrict__ wr_b, float* __restrict__ relmsg) {
    int l = blockIdx.x / NRELS;
    int r = blockIdx.x % NRELS;
    int o = threadIdx.x;
    float wv = Wrel[r*HIDD + o];
    __shared__ float red[128];
    red[o] = wv * wr_w[l*HIDD + o];
    __syncthreads();
    for (int s = 64; s > 0; s >>= 1) {
        if (o < s) red[o] += red[o + s];
        __syncthreads();
    }
    float wrel = red[0] + wr_b[l];
    relmsg[((long)l*NRELS + r)*HIDD + o] = wrel * wv;
}

__global__ void k_xinit(const float* __restrict__ Wnode, const int* __restrict__ nid,
                        float* __restrict__ x, __bf16* __restrict__ xb) {
    int t = blockIdx.x*256 + threadIdx.x;
    if (t >= WS_N*32) return;
    int i = t >> 5;
    int d = t & 31;
    float4 v = ((const float4*)Wnode)[nid[i]*32 + d];
    ((float4*)x)[i*32 + d] = v;
    bf16x4 b;
    b[0] = (__bf16)v.x; b[1] = (__bf16)v.y; b[2] = (__bf16)v.z; b[3] = (__bf16)v.w;
    ((bf16x4*)xb)[i*32 + d] = b;
}

__global__ __launch_bounds__(256) void k_beta(const float* __restrict__ visit, const float* __restrict__ beta_w,
                                              const float* __restrict__ beta_b, float* __restrict__ beta) {
    int id = blockIdx.x;                 // l*640 + b*20 + v
    int l = id / (BV*VV);
    int rem = id % (BV*VV);
    int b = rem / VV;
    int v = rem % VV;
    const float* row = visit + ((long)b*VV + v) * NNODES;
    const float* wr  = beta_w + (long)l * NNODES;
    float s = 0.f;
    for (int n = threadIdx.x; n < NNODES; n += 256) s += row[n] * wr[n];
    __shared__ float red[256];
    red[threadIdx.x] = s; __syncthreads();
    for (int o = 128; o > 0; o >>= 1) {
        if (threadIdx.x < o) red[threadIdx.x] += red[threadIdx.x + o];
        __syncthreads();
    }
    if (threadIdx.x == 0) {
        float lam = __expf(DECAYF * (float)(VV - v));
        beta[id] = tanhf(red[0] + beta_b[l]) * lam;
    }
}

__global__ __launch_bounds__(256) void k_attnpool(const float* __restrict__ z, const float* __restrict__ beta,
                                                  float* __restrict__ attn) {
    int m = blockIdx.x*256 + threadIdx.x;
    int b = blockIdx.y;
    int l = blockIdx.z;
    if (m >= NNODES) return;
    const float* zb  = z + ((long)l*BV*VV + b*VV) * NNODES + m;
    const float* bet = beta + (l*BV + b) * VV;
    float zv[VV];
    float mx = -1e30f;
    #pragma unroll
    for (int v = 0; v < VV; v++) { zv[v] = zb[(long)v * NNODES]; mx = fmaxf(mx, zv[v]); }
    float s = 0.f, ws = 0.f;
    #pragma unroll
    for (int v = 0; v < VV; v++) {
        float e = __expf(zv[v] - mx);
        s += e;
        ws += e * bet[v];
    }
    attn[((long)l*BV + b) * NNODES + m] = ws / s;
}

__global__ void k_attn_node(const float* __restrict__ attn, const int* __restrict__ batch,
                            const int* __restrict__ nid, float* __restrict__ an) {
    int i = blockIdx.x*256 + threadIdx.x;
    int l = blockIdx.y;
    if (i >= WS_N) return;
    an[(long)l*WS_N + i] = attn[((long)l*BV + batch[i]) * NNODES + nid[i]];
}

// ---------------- message + aggregate (wave per dst node, bf16 gather) ----------------
__global__ __launch_bounds__(256) void k_agg(const float* __restrict__ x, const __bf16* __restrict__ xb,
                                             const float* __restrict__ an,
                                             const float* __restrict__ relmsg_l, const int* __restrict__ offs,
                                             const int* __restrict__ ssrc, const int* __restrict__ srel,
                                             float* __restrict__ outb) {
    int node = blockIdx.x*4 + (threadIdx.x >> 6);
    int lane = threadIdx.x & 63;
    if (node >= WS_N) return;
    int e0 = offs[node], e1 = offs[node + 1];
    const float2* x2  = (const float2*)x;
    const bf16x2* xb2 = (const bf16x2*)xb;
    const float2* rm2 = (const float2*)relmsg_l;
    float2 acc = {0.f, 0.f};
    int e = e0;
    for (; e + 3 < e1; e += 4) {
        int s0 = ssrc[e],   s1 = ssrc[e+1], s2 = ssrc[e+2], s3 = ssrc[e+3];
        int r0 = srel[e],   r1 = srel[e+1], r2 = srel[e+2], r3 = srel[e+3];
        float a0 = an[s0], a1 = an[s1], a2 = an[s2], a3 = an[s3];
        bf16x2 g0 = xb2[s0*64 + lane], g1 = xb2[s1*64 + lane];
        bf16x2 g2 = xb2[s2*64 + lane], g3 = xb2[s3*64 + lane];
        float2 m0 = rm2[r0*64 + lane], m1 = rm2[r1*64 + lane];
        float2 m2 = rm2[r2*64 + lane], m3 = rm2[r3*64 + lane];
        acc.x += fmaxf((float)g0[0]*a0 + m0.x, 0.f) + fmaxf((float)g1[0]*a1 + m1.x, 0.f)
               + fmaxf((float)g2[0]*a2 + m2.x, 0.f) + fmaxf((float)g3[0]*a3 + m3.x, 0.f);
        acc.y += fmaxf((float)g0[1]*a0 + m0.y, 0.f) + fmaxf((float)g1[1]*a1 + m1.y, 0.f)
               + fmaxf((float)g2[1]*a2 + m2.y, 0.f) + fmaxf((float)g3[1]*a3 + m3.y, 0.f);
    }
    for (; e < e1; e++) {
        int sa = ssrc[e], ra = srel[e];
        float aa = an[sa];
        bf16x2 ga = xb2[sa*64 + lane];
        float2 va = rm2[ra*64 + lane];
        acc.x += fmaxf((float)ga[0]*aa + va.x, 0.f);
        acc.y += fmaxf((float)ga[1]*aa + va.y, 0.f);
    }
    float2 xo = x2[node*64 + lane];
    acc.x += xo.x; acc.y += xo.y;
    ((float2*)outb)[node*64 + lane] = acc;
}

// ---------------- final stage ----------------
__global__ void k_bstart(const int* __restrict__ batch, int* __restrict__ bstart) {
    int t = threadIdx.x;
    if (t > BV) return;
    int lo = 0, hi = WS_N;
    while (lo < hi) {
        int mid = (lo + hi) >> 1;
        if (batch[mid] < t) lo = mid + 1; else hi = mid;
    }
    bstart[t] = lo;
}

// mean-pool phase 1: parallel partial sums over row chunks, batch-run flush via atomics.
__global__ __launch_bounds__(256) void k_pool_partial(const float* __restrict__ x,
                                                      const int* __restrict__ batch,
                                                      float* __restrict__ xgsum) {
    int r0 = blockIdx.x * 128;
    int d = threadIdx.x & 127;
    int rofs = threadIdx.x >> 7;       // 0 or 1
    int r1 = min(r0 + 128, WS_N);
    float acc = 0.f;
    int curb = -1;
    for (int i = r0 + rofs; i < r1; i += 2) {
        int b = batch[i];
        if (b != curb) {
            if (curb >= 0) atomicAdd(&xgsum[curb*HIDD + d], acc);
            acc = 0.f; curb = b;
        }
        acc += x[(long)i*HIDD + d];
    }
    if (curb >= 0) atomicAdd(&xgsum[curb*HIDD + d], acc);
}

__global__ __launch_bounds__(128) void k_pool_fin(const float* __restrict__ xgsum,
                                                  const int* __restrict__ bstart,
                                                  float* __restrict__ xg) {
    int b = blockIdx.x;
    int d = threadIdx.x;
    int cnt = bstart[b+1] - bstart[b];
    xg[b*HIDD + d] = xgsum[b*HIDD + d] / (float)max(cnt, 1);
}

// x_node phase 1: ehr @ node_emb partial sums + ehr row-sum, parallel over n-chunks.
__global__ __launch_bounds__(128) void k_ehrpool(const float* __restrict__ ehr,
                                                 const float* __restrict__ node_emb,
                                                 float* __restrict__ xnsum, float* __restrict__ esum) {
    int b = blockIdx.y;
    int c = blockIdx.x;
    int d = threadIdx.x;
    int n0 = c * (NNODES/16), n1 = n0 + (NNODES/16);
    float acc = 0.f;
    for (int n = n0; n < n1; n++) {
        acc += ehr[b*NNODES + n] * node_emb[(long)n*HIDD + d];
    }
    atomicAdd(&xnsum[b*HIDD + d], acc);
    float s = 0.f;
    for (int n = n0 + d; n < n1; n += 128) s += ehr[b*NNODES + n];
    __shared__ float red[128];
    red[d] = s; __syncthreads();
    for (int o = 64; o > 0; o >>= 1) {
        if (d < o) red[d] += red[d + o];
        __syncthreads();
    }
    if (d == 0) atomicAdd(&esum[b], red[0]);
}

__global__ __launch_bounds__(128) void k_xnode_fin(const float* __restrict__ xnsum,
                                                   const float* __restrict__ esum,
                                                   const float* __restrict__ lin_w,
                                                   const float* __restrict__ lin_b,
                                                   float* __restrict__ xn) {
    int b = blockIdx.x;
    int d = threadIdx.x;
    __shared__ float t1[128];
    t1[d] = xnsum[b*HIDD + d] / esum[b];
    __syncthreads();
    float o2 = lin_b[d];
    for (int k2 = 0; k2 < HIDD; k2++) o2 += t1[k2] * lin_w[d*HIDD + k2];
    xn[b*HIDD + d] = o2;
}

__global__ __launch_bounds__(128) void k_mlp(const float* __restrict__ xg, const float* __restrict__ xn,
                                             const float* __restrict__ mlp_w, const float* __restrict__ mlp_b,
                                             float* __restrict__ out) {
    int b = blockIdx.x;
    int t = threadIdx.x;
    __shared__ float cat[2*HIDD];
    cat[t] = xg[b*HIDD + t];
    cat[HIDD + t] = xn[b*HIDD + t];
    __syncthreads();
    if (t < OUTD) {
        float acc = mlp_b[t];
        for (int j = 0; j < 2*HIDD; j++) acc += cat[j] * mlp_w[t*2*HIDD + j];
        out[b*OUTD + t] = acc;
    }
}

// ---------------- launcher ----------------
extern "C" void kernel_launch(void* const* d_in, const int* in_sizes, int n_in,
                              void* d_out, int out_size, void* d_ws, size_t ws_size,
                              hipStream_t stream)
{
    const float* node_emb = (const float*)d_in[0];
    const float* rel_emb  = (const float*)d_in[1];
    const float* lin_w    = (const float*)d_in[2];
    const float* lin_b    = (const float*)d_in[3];
    const float* alpha_w  = (const float*)d_in[4];
    // d_in[5] alpha_b: shift-invariant under softmax over v -> unused
    const float* beta_w   = (const float*)d_in[6];
    const float* beta_b   = (const float*)d_in[7];
    const float* wr_w     = (const float*)d_in[8];
    const float* wr_b     = (const float*)d_in[9];
    const float* conv_w   = (const float*)d_in[10];
    const float* conv_b   = (const float*)d_in[11];
    const float* mlp_w    = (const float*)d_in[12];
    const float* mlp_b    = (const float*)d_in[13];
    const float* visit    = (const float*)d_in[14];
    const float* ehr      = (const float*)d_in[15];
    const int* node_ids   = (const int*)d_in[16];
    const int* rel_ids    = (const int*)d_in[17];
    const int* ei         = (const int*)d_in[18];
    const int* batch      = (const int*)d_in[19];
    const int* esrc = ei;
    const int* edst = ei + WS_E;
    float* out = (float*)d_out;

    char* p = (char*)d_ws;
    auto take = [&](size_t bytes) -> char* {
        char* q = p;
        p += (bytes + 255) & ~(size_t)255;
        return q;
    };
    float* x      = (float*)take((size_t)WS_N*HIDD*4);             // 25.6 MB
    __bf16* xb    = (__bf16*)take((size_t)WS_N*HIDD*2);            // 12.8 MB bf16 shadow of x
    float* zbuf   = (float*)take((size_t)LL*BV*VV*NNODES*4);       // 30.7 MB (aggbuf aliases: z dead after attnpool)
    float* aggbuf = zbuf;
    float* attn   = (float*)take((size_t)LL*BV*NNODES*4);
    float* betab  = (float*)take((size_t)LL*BV*VV*4);
    float* attnnd = (float*)take((size_t)LL*WS_N*4);
    float* Wnode  = (float*)take((size_t)NNODES*HIDD*4);
    float* Wrel   = (float*)take((size_t)NRELS*HIDD*4);
    float* relmsg = (float*)take((size_t)LL*NRELS*HIDD*4);
    // small accumulators zeroed with ONE memset: keep contiguous
    float* xgsum  = (float*)take((size_t)BV*HIDD*4);
    float* xnsum  = (float*)take((size_t)BV*HIDD*4);
    float* esum   = (float*)take((size_t)BV*4);
    size_t small_zero_bytes = (size_t)((char*)(esum + BV) - (char*)xgsum);
    float* xg     = (float*)take((size_t)BV*HIDD*4);
    float* xn     = (float*)take((size_t)BV*HIDD*4);
    int* deg      = (int*)take((size_t)WS_N*4);
    int* offs     = (int*)take((size_t)(WS_N+1)*4);
    int* cursor   = (int*)take((size_t)WS_N*4);
    int* ssrc     = (int*)take((size_t)WS_E*4);
    int* srel     = (int*)take((size_t)WS_E*4);
    int* bstart   = (int*)take((size_t)(BV+1)*4);
    if ((size_t)(p - (char*)d_ws) > ws_size) return;  // ws too small: leave output poisoned (visible failure)

    (void)hipMemsetAsync(deg, 0, (size_t)WS_N*4, stream);
    (void)hipMemsetAsync(xgsum, 0, small_zero_bytes, stream);

    // CSR by dst (graph is layer-invariant)
    k_count<<<dim3((WS_E+255)/256), 256, 0, stream>>>(edst, deg);
    k_scan<<<1, 1024, 0, stream>>>(deg, offs, cursor, WS_N);
    k_fill<<<dim3((WS_E+255)/256), 256, 0, stream>>>(edst, esrc, rel_ids, cursor, ssrc, srel);

    // Wnode = node_emb @ lin_w^T + lin_b ; Wrel likewise (split-bf16 => ~f32 accuracy)
    gemm_bt<1,0,1,0><<<dim3((NNODES+BM-1)/BM, 1, 1), 256, 0, stream>>>(
        node_emb, lin_w, Wnode, lin_b, nullptr, NNODES, HIDD, HIDD);
    gemm_bt<1,0,1,0><<<dim3((NRELS+BM-1)/BM, 1, 1), 256, 0, stream>>>(
        rel_emb, lin_w, Wrel, lin_b, nullptr, NRELS, HIDD, HIDD);
    k_relmsg<<<dim3(LL*NRELS), 128, 0, stream>>>(Wrel, wr_w, wr_b, relmsg);
    k_xinit<<<dim3((WS_N*32+255)/256), 256, 0, stream>>>(Wnode, node_ids, x, xb);
    k_beta<<<dim3(LL*BV*VV), 256, 0, stream>>>(visit, beta_w, beta_b, betab);

    // z[l, b*V+v, m] = visit2d @ alpha_w[l]^T  (XCD-grouped swizzle, direct store)
    gemm_alpha<<<dim3(480), 256, 0, stream>>>(visit, alpha_w, zbuf);

    k_attnpool<<<dim3((NNODES+255)/256, BV, LL), 256, 0, stream>>>(zbuf, betab, attn);
    k_attn_node<<<dim3((WS_N+255)/256, LL), 256, 0, stream>>>(attn, batch, node_ids, attnnd);

    for (int l = 0; l < LL; l++) {
        k_agg<<<dim3((WS_N+3)/4), 256, 0, stream>>>(
            x, xb, attnnd + (size_t)l*WS_N, relmsg + (size_t)l*NRELS*HIDD, offs, ssrc, srel, aggbuf);
        gemm_bt<1,1,1,1><<<dim3((WS_N+BM-1)/BM, 1, 1), 256, 0, stream>>>(
            aggbuf, conv_w + (size_t)l*HIDD*HIDD, x, conv_b + (size_t)l*HIDD, xb,
            WS_N, HIDD, HIDD);
    }

    k_bstart<<<1, 64, 0, stream>>>(batch, bstart);
    k_pool_partial<<<dim3((WS_N+127)/128), 256, 0, stream>>>(x, batch, xgsum);
    k_pool_fin<<<BV, 128, 0, stream>>>(xgsum, bstart, xg);
    k_ehrpool<<<dim3(16, BV), 128, 0, stream>>>(ehr, node_emb, xnsum, esum);
    k_xnode_fin<<<BV, 128, 0, stream>>>(xnsum, esum, lin_w, lin_b, xn);
    k_mlp<<<BV, 128, 0, stream>>>(xg, xn, mlp_w, mlp_b, out);
}

// Round 4
// 952.844 us; speedup vs baseline: 1.6872x; 1.0867x over previous
//
#include <hip/hip_runtime.h>
#include <hip/hip_bf16.h>
#include <stdint.h>

// ---------------- problem constants ----------------
#define LL      3
#define NNODES  4000
#define NRELS   200
#define VV      20
#define EMB     128
#define HIDD    128
#define OUTD    100
#define WS_N    50000
#define WS_E    800000
#define BV      32
#define DECAYF  0.03f

// ---------------- GEMM (C[M,N] = A[M,K] * B[N,K]^T), bf16 MFMA ----------------
typedef __bf16 bf16x8 __attribute__((ext_vector_type(8)));
typedef __bf16 bf16x4 __attribute__((ext_vector_type(4)));
typedef __bf16 bf16x2 __attribute__((ext_vector_type(2)));
typedef float  f32x4  __attribute__((ext_vector_type(4)));

#define BM 128
#define BN 128
#define BKG 32
#define LSTR 40   // LDS row stride in bf16 elements (32 + 8 pad)

template<int SPLIT>
__device__ __forceinline__ void stage_tile(const float* __restrict__ G, int rows, int Kdim,
                                           int r0, int kb, int k1, __bf16* Sh, __bf16* Sl, int tid)
{
    const int sr  = tid >> 1;          // row 0..127
    const int skc = (tid & 1) * 16;    // k offset 0 or 16
    const int gr  = r0 + sr;
    const int gk  = kb + skc;
    float va[16];
    if (gr < rows && gk + 16 <= k1) {
        const float4* p4 = (const float4*)(G + (long)gr * Kdim + gk);
        #pragma unroll
        for (int q = 0; q < 4; q++) {
            float4 f = p4[q];
            va[4*q+0] = f.x; va[4*q+1] = f.y; va[4*q+2] = f.z; va[4*q+3] = f.w;
        }
    } else {
        #pragma unroll
        for (int j = 0; j < 16; j++) {
            int kk = gk + j;
            va[j] = (gr < rows && kk < k1) ? G[(long)gr * Kdim + kk] : 0.0f;
        }
    }
    bf16x8 h[2], lo[2];
    #pragma unroll
    for (int half = 0; half < 2; half++) {
        #pragma unroll
        for (int j = 0; j < 8; j++) {
            float v = va[half*8 + j];
            __bf16 hi = (__bf16)v;
            h[half][j]  = hi;
            lo[half][j] = (__bf16)(v - (float)hi);
        }
    }
    *(bf16x8*)&Sh[sr*LSTR + skc]     = h[0];
    *(bf16x8*)&Sh[sr*LSTR + skc + 8] = h[1];
    if (SPLIT) {
        *(bf16x8*)&Sl[sr*LSTR + skc]     = lo[0];
        *(bf16x8*)&Sl[sr*LSTR + skc + 8] = lo[1];
    }
}

template<int SPLIT, int RELU, int BIAS, int WRITEB>
__global__ __launch_bounds__(256)
void gemm_bt(const float* __restrict__ Ag, const float* __restrict__ Bg,
             float* __restrict__ Cg, const float* __restrict__ bias,
             __bf16* __restrict__ Xb, int M, int N, int K)
{
    __shared__ __bf16 Ah[BM*LSTR];
    __shared__ __bf16 Bh[BN*LSTR];
    __shared__ __bf16 Alo[SPLIT ? BM*LSTR : 1];
    __shared__ __bf16 Blo[SPLIT ? BN*LSTR : 1];

    const int tid = threadIdx.x;
    const int m0 = blockIdx.x * BM;
    const int n0 = blockIdx.y * BN;

    const int wave = tid >> 6;
    const int lane = tid & 63;
    const int wm = (wave & 1) * 64;
    const int wn = (wave >> 1) * 64;
    const int lr = lane & 15;
    const int kq = lane >> 4;

    f32x4 acc[4][4];
    #pragma unroll
    for (int i = 0; i < 4; i++)
        #pragma unroll
        for (int j = 0; j < 4; j++)
            acc[i][j] = (f32x4){0.f, 0.f, 0.f, 0.f};

    for (int kb = 0; kb < K; kb += BKG) {
        stage_tile<SPLIT>(Ag, M, K, m0, kb, K, Ah, Alo, tid);
        stage_tile<SPLIT>(Bg, N, K, n0, kb, K, Bh, Blo, tid);
        __syncthreads();

        bf16x8 af[4], bfr[4];
        #pragma unroll
        for (int i = 0; i < 4; i++) {
            af[i]  = *(const bf16x8*)&Ah[(wm + i*16 + lr)*LSTR + kq*8];
            bfr[i] = *(const bf16x8*)&Bh[(wn + i*16 + lr)*LSTR + kq*8];
        }
        #pragma unroll
        for (int i = 0; i < 4; i++)
            #pragma unroll
            for (int j = 0; j < 4; j++)
                acc[i][j] = __builtin_amdgcn_mfma_f32_16x16x32_bf16(af[i], bfr[j], acc[i][j], 0, 0, 0);

        if (SPLIT) {
            bf16x8 al[4], bl[4];
            #pragma unroll
            for (int i = 0; i < 4; i++) {
                al[i] = *(const bf16x8*)&Alo[(wm + i*16 + lr)*LSTR + kq*8];
                bl[i] = *(const bf16x8*)&Blo[(wn + i*16 + lr)*LSTR + kq*8];
            }
            #pragma unroll
            for (int i = 0; i < 4; i++)
                #pragma unroll
                for (int j = 0; j < 4; j++) {
                    acc[i][j] = __builtin_amdgcn_mfma_f32_16x16x32_bf16(af[i], bl[j], acc[i][j], 0, 0, 0);
                    acc[i][j] = __builtin_amdgcn_mfma_f32_16x16x32_bf16(al[i], bfr[j], acc[i][j], 0, 0, 0);
                }
        }
        __syncthreads();
    }

    // epilogue: C/D layout col=lane&15, row=(lane>>4)*4+reg (m89/m91-verified)
    #pragma unroll
    for (int i = 0; i < 4; i++) {
        const int row_b = m0 + wm + i*16 + kq*4;
        #pragma unroll
        for (int j = 0; j < 4; j++) {
            const int col = n0 + wn + j*16 + lr;
            if (col < N) {
                #pragma unroll
                for (int r = 0; r < 4; r++) {
                    const int row = row_b + r;
                    if (row < M) {
                        float v = acc[i][j][r];
                        if (BIAS) v += bias[col];
                        if (RELU) v = fmaxf(v, 0.0f);
                        Cg[(long)row*N + col] = v;
                        if (WRITEB) Xb[(long)row*N + col] = (__bf16)v;
                    }
                }
            }
        }
    }
}

// ---------------- alpha GEMM: z[l,row,col] = visit[row,:] . alpha_w[l][col,:] ----------------
// Split-K=2 (K halves 2016/1984, partial sums to z0/z1, summed in k_attnpool) for
// occupancy: 960 blocks = ~3.75 blocks/CU (R3's 480 ran at 21% occupancy, latency-bound).
// XCD-grouped swizzle retained: assuming round-robin block->XCD (id%8), the 5 m-blocks
// sharing one alpha_w B-tile chunk land on the SAME XCD (L2 reuse; R3: FETCH 562->134 MB).
__global__ __launch_bounds__(256)
void gemm_alpha(const float* __restrict__ visit, const float* __restrict__ alpha_w,
                float* __restrict__ z0, float* __restrict__ z1)
{
    __shared__ __bf16 Ah[BM*LSTR];
    __shared__ __bf16 Bh[BN*LSTR];

    const int id   = blockIdx.x;      // 0..959
    const int xcd  = id & 7;
    const int slot = id >> 3;         // 0..119
    const int mi   = slot % 5;        // 0..4
    const int gix  = slot / 5;        // 0..23
    const int g    = xcd * 24 + gix;  // 0..191  (l, kh, ni) group
    const int ni   = g & 31;          // 0..31
    const int lkh  = g >> 5;          // 0..5
    const int l    = lkh >> 1;        // 0..2
    const int kh   = lkh & 1;         // 0..1

    const float* Bg = alpha_w + (long)l * NNODES * NNODES;
    float*       Cg = (kh ? z1 : z0) + (long)l * (BV*VV) * NNODES;
    const int m0 = mi * BM;
    const int n0 = ni * BN;
    const int k0 = kh ? 2016 : 0;     // both multiples of BKG pieces (63/62 iters)
    const int k1 = kh ? NNODES : 2016;

    const int tid = threadIdx.x;
    const int wave = tid >> 6;
    const int lane = tid & 63;
    const int wm = (wave & 1) * 64;
    const int wn = (wave >> 1) * 64;
    const int lr = lane & 15;
    const int kq = lane >> 4;

    f32x4 acc[4][4];
    #pragma unroll
    for (int i = 0; i < 4; i++)
        #pragma unroll
        for (int j = 0; j < 4; j++)
            acc[i][j] = (f32x4){0.f, 0.f, 0.f, 0.f};

    for (int kb = k0; kb < k1; kb += BKG) {
        stage_tile<0>(visit, BV*VV, NNODES, m0, kb, k1, Ah, nullptr, tid);
        stage_tile<0>(Bg, NNODES, NNODES, n0, kb, k1, Bh, nullptr, tid);
        __syncthreads();

        bf16x8 af[4], bfr[4];
        #pragma unroll
        for (int i = 0; i < 4; i++) {
            af[i]  = *(const bf16x8*)&Ah[(wm + i*16 + lr)*LSTR + kq*8];
            bfr[i] = *(const bf16x8*)&Bh[(wn + i*16 + lr)*LSTR + kq*8];
        }
        #pragma unroll
        for (int i = 0; i < 4; i++)
            #pragma unroll
            for (int j = 0; j < 4; j++)
                acc[i][j] = __builtin_amdgcn_mfma_f32_16x16x32_bf16(af[i], bfr[j], acc[i][j], 0, 0, 0);
        __syncthreads();
    }

    #pragma unroll
    for (int i = 0; i < 4; i++) {
        const int row_b = m0 + wm + i*16 + kq*4;   // rows < 640 always
        #pragma unroll
        for (int j = 0; j < 4; j++) {
            const int col = n0 + wn + j*16 + lr;
            if (col < NNODES) {
                #pragma unroll
                for (int r = 0; r < 4; r++)
                    Cg[(long)(row_b + r)*NNODES + col] = acc[i][j][r];
            }
        }
    }
}

// ---------------- CSR build ----------------
__global__ void k_count(const int* __restrict__ dst, int* __restrict__ deg) {
    int e = blockIdx.x*256 + threadIdx.x;
    if (e < WS_E) atomicAdd(&deg[dst[e]], 1);
}

__global__ __launch_bounds__(1024) void k_scan(const int* __restrict__ deg, int* __restrict__ offs,
                                               int* __restrict__ cursor, int n) {
    __shared__ int part[1024];
    int t = threadIdx.x;
    int chunk = (n + 1023) / 1024;
    int s0 = t * chunk;
    int s1 = min(s0 + chunk, n);
    int s = 0;
    for (int i = s0; i < s1; i++) s += deg[i];
    part[t] = s; __syncthreads();
    for (int off = 1; off < 1024; off <<= 1) {
        int v = part[t];
        if (t >= off) v += part[t - off];
        __syncthreads();
        part[t] = v;
        __syncthreads();
    }
    int pre = (t == 0) ? 0 : part[t - 1];
    for (int i = s0; i < s1; i++) { offs[i] = pre; cursor[i] = pre; pre += deg[i]; }
    if (t == 1023) offs[n] = pre;
}

__global__ void k_fill(const int* __restrict__ dst, const int* __restrict__ src,
                       const int* __restrict__ rel, int* __restrict__ cursor,
                       int* __restrict__ ssrc, int* __restrict__ srel) {
    int e = blockIdx.x*256 + threadIdx.x;
    if (e < WS_E) {
        int d = dst[e];
        int p = atomicAdd(&cursor[d], 1);
        ssrc[p] = src[e];
        srel[p] = rel[e];
    }
}

// ---------------- small precompute kernels ----------------
__global__ __launch_bounds__(128) void k_relmsg(const float* __restrict__ Wrel, const float* __restrict__ wr_w,
                                                const float* __restrict__ wr_b, __bf16* __restrict__ relmsg) {
    int l = blockIdx.x / NRELS;
    int r = blockIdx.x % NRELS;
    int o = threadIdx.x;
    float wv = Wrel[r*HIDD + o];
    __shared__ float red[128];
    red[o] = wv * wr_w[l*HIDD + o];
    __syncthreads();
    for (int s = 64; s > 0; s >>= 1) {
        if (o < s) red[o] += red[o + s];
        __syncthreads();
    }
    float wrel = red[0] + wr_b[l];
    relmsg[((long)l*NRELS + r)*HIDD + o] = (__bf16)(wrel * wv);
}

__global__ void k_xinit(const float* __restrict__ Wnode, const int* __restrict__ nid,
                        float* __restrict__ x, __bf16* __restrict__ xb) {
    int t = blockIdx.x*256 + threadIdx.x;
    if (t >= WS_N*32) return;
    int i = t >> 5;
    int d = t & 31;
    float4 v = ((const float4*)Wnode)[nid[i]*32 + d];
    ((float4*)x)[i*32 + d] = v;
    bf16x4 b;
    b[0] = (__bf16)v.x; b[1] = (__bf16)v.y; b[2] = (__bf16)v.z; b[3] = (__bf16)v.w;
    ((bf16x4*)xb)[i*32 + d] = b;
}

__global__ __launch_bounds__(256) void k_beta(const float* __restrict__ visit, const float* __restrict__ beta_w,
                                              const float* __restrict__ beta_b, float* __restrict__ beta) {
    int id = blockIdx.x;                 // l*640 + b*20 + v
    int l = id / (BV*VV);
    int rem = id % (BV*VV);
    int b = rem / VV;
    int v = rem % VV;
    const float* row = visit + ((long)b*VV + v) * NNODES;
    const float* wr  = beta_w + (long)l * NNODES;
    float s = 0.f;
    for (int n = threadIdx.x; n < NNODES; n += 256) s += row[n] * wr[n];
    __shared__ float red[256];
    red[threadIdx.x] = s; __syncthreads();
    for (int o = 128; o > 0; o >>= 1) {
        if (threadIdx.x < o) red[threadIdx.x] += red[threadIdx.x + o];
        __syncthreads();
    }
    if (threadIdx.x == 0) {
        float lam = __expf(DECAYF * (float)(VV - v));
        beta[id] = tanhf(red[0] + beta_b[l]) * lam;
    }
}

__global__ __launch_bounds__(256) void k_attnpool(const float* __restrict__ z0, const float* __restrict__ z1,
                                                  const float* __restrict__ beta, float* __restrict__ attn) {
    int m = blockIdx.x*256 + threadIdx.x;
    int b = blockIdx.y;
    int l = blockIdx.z;
    if (m >= NNODES) return;
    const long base = ((long)l*BV*VV + b*VV) * NNODES + m;
    const float* zb0 = z0 + base;
    const float* zb1 = z1 + base;
    const float* bet = beta + (l*BV + b) * VV;
    float zv[VV];
    float mx = -1e30f;
    #pragma unroll
    for (int v = 0; v < VV; v++) {
        zv[v] = zb0[(long)v * NNODES] + zb1[(long)v * NNODES];
        mx = fmaxf(mx, zv[v]);
    }
    float s = 0.f, ws = 0.f;
    #pragma unroll
    for (int v = 0; v < VV; v++) {
        float e = __expf(zv[v] - mx);
        s += e;
        ws += e * bet[v];
    }
    attn[((long)l*BV + b) * NNODES + m] = ws / s;
}

__global__ void k_attn_node(const float* __restrict__ attn, const int* __restrict__ batch,
                            const int* __restrict__ nid, float* __restrict__ an) {
    int i = blockIdx.x*256 + threadIdx.x;
    int l = blockIdx.y;
    if (i >= WS_N) return;
    an[(long)l*WS_N + i] = attn[((long)l*BV + batch[i]) * NNODES + nid[i]];
}

// ---------------- message + aggregate (wave per dst node, bf16 gather + bf16 relmsg) ----------------
__global__ __launch_bounds__(256) void k_agg(const float* __restrict__ x, const __bf16* __restrict__ xb,
                                             const float* __restrict__ an,
                                             const __bf16* __restrict__ relmsg_l, const int* __restrict__ offs,
                                             const int* __restrict__ ssrc, const int* __restrict__ srel,
                                             float* __restrict__ outb) {
    int node = blockIdx.x*4 + (threadIdx.x >> 6);
    int lane = threadIdx.x & 63;
    if (node >= WS_N) return;
    int e0 = offs[node], e1 = offs[node + 1];
    const float2* x2  = (const float2*)x;
    const bf16x2* xb2 = (const bf16x2*)xb;
    const bf16x2* rm2 = (const bf16x2*)relmsg_l;
    float2 acc = {0.f, 0.f};
    int e = e0;
    for (; e + 3 < e1; e += 4) {
        int s0 = ssrc[e],   s1 = ssrc[e+1], s2 = ssrc[e+2], s3 = ssrc[e+3];
        int r0 = srel[e],   r1 = srel[e+1], r2 = srel[e+2], r3 = srel[e+3];
        float a0 = an[s0], a1 = an[s1], a2 = an[s2], a3 = an[s3];
        bf16x2 g0 = xb2[s0*64 + lane], g1 = xb2[s1*64 + lane];
        bf16x2 g2 = xb2[s2*64 + lane], g3 = xb2[s3*64 + lane];
        bf16x2 m0 = rm2[r0*64 + lane], m1 = rm2[r1*64 + lane];
        bf16x2 m2 = rm2[r2*64 + lane], m3 = rm2[r3*64 + lane];
        acc.x += fmaxf((float)g0[0]*a0 + (float)m0[0], 0.f) + fmaxf((float)g1[0]*a1 + (float)m1[0], 0.f)
               + fmaxf((float)g2[0]*a2 + (float)m2[0], 0.f) + fmaxf((float)g3[0]*a3 + (float)m3[0], 0.f);
        acc.y += fmaxf((float)g0[1]*a0 + (float)m0[1], 0.f) + fmaxf((float)g1[1]*a1 + (float)m1[1], 0.f)
               + fmaxf((float)g2[1]*a2 + (float)m2[1], 0.f) + fmaxf((float)g3[1]*a3 + (float)m3[1], 0.f);
    }
    for (; e < e1; e++) {
        int sa = ssrc[e], ra = srel[e];
        float aa = an[sa];
        bf16x2 ga = xb2[sa*64 + lane];
        bf16x2 va = rm2[ra*64 + lane];
        acc.x += fmaxf((float)ga[0]*aa + (float)va[0], 0.f);
        acc.y += fmaxf((float)ga[1]*aa + (float)va[1], 0.f);
    }
    float2 xo = x2[node*64 + lane];
    acc.x += xo.x; acc.y += xo.y;
    ((float2*)outb)[node*64 + lane] = acc;
}

// ---------------- final stage ----------------
__global__ void k_bstart(const int* __restrict__ batch, int* __restrict__ bstart) {
    int t = threadIdx.x;
    if (t > BV) return;
    int lo = 0, hi = WS_N;
    while (lo < hi) {
        int mid = (lo + hi) >> 1;
        if (batch[mid] < t) lo = mid + 1; else hi = mid;
    }
    bstart[t] = lo;
}

// mean-pool phase 1: parallel partial sums over row chunks, batch-run flush via atomics.
__global__ __launch_bounds__(256) void k_pool_partial(const float* __restrict__ x,
                                                      const int* __restrict__ batch,
                                                      float* __restrict__ xgsum) {
    int r0 = blockIdx.x * 128;
    int d = threadIdx.x & 127;
    int rofs = threadIdx.x >> 7;       // 0 or 1
    int r1 = min(r0 + 128, WS_N);
    float acc = 0.f;
    int curb = -1;
    for (int i = r0 + rofs; i < r1; i += 2) {
        int b = batch[i];
        if (b != curb) {
            if (curb >= 0) atomicAdd(&xgsum[curb*HIDD + d], acc);
            acc = 0.f; curb = b;
        }
        acc += x[(long)i*HIDD + d];
    }
    if (curb >= 0) atomicAdd(&xgsum[curb*HIDD + d], acc);
}

__global__ __launch_bounds__(128) void k_pool_fin(const float* __restrict__ xgsum,
                                                  const int* __restrict__ bstart,
                                                  float* __restrict__ xg) {
    int b = blockIdx.x;
    int d = threadIdx.x;
    int cnt = bstart[b+1] - bstart[b];
    xg[b*HIDD + d] = xgsum[b*HIDD + d] / (float)max(cnt, 1);
}

// x_node phase 1: ehr @ node_emb partial sums + ehr row-sum, parallel over n-chunks.
__global__ __launch_bounds__(128) void k_ehrpool(const float* __restrict__ ehr,
                                                 const float* __restrict__ node_emb,
                                                 float* __restrict__ xnsum, float* __restrict__ esum) {
    int b = blockIdx.y;
    int c = blockIdx.x;
    int d = threadIdx.x;
    int n0 = c * (NNODES/16), n1 = n0 + (NNODES/16);
    float acc = 0.f;
    for (int n = n0; n < n1; n++) {
        acc += ehr[b*NNODES + n] * node_emb[(long)n*HIDD + d];
    }
    atomicAdd(&xnsum[b*HIDD + d], acc);
    float s = 0.f;
    for (int n = n0 + d; n < n1; n += 128) s += ehr[b*NNODES + n];
    __shared__ float red[128];
    red[d] = s; __syncthreads();
    for (int o = 64; o > 0; o >>= 1) {
        if (d < o) red[d] += red[d + o];
        __syncthreads();
    }
    if (d == 0) atomicAdd(&esum[b], red[0]);
}

__global__ __launch_bounds__(128) void k_xnode_fin(const float* __restrict__ xnsum,
                                                   const float* __restrict__ esum,
                                                   const float* __restrict__ lin_w,
                                                   const float* __restrict__ lin_b,
                                                   float* __restrict__ xn) {
    int b = blockIdx.x;
    int d = threadIdx.x;
    __shared__ float t1[128];
    t1[d] = xnsum[b*HIDD + d] / esum[b];
    __syncthreads();
    float o2 = lin_b[d];
    for (int k2 = 0; k2 < HIDD; k2++) o2 += t1[k2] * lin_w[d*HIDD + k2];
    xn[b*HIDD + d] = o2;
}

__global__ __launch_bounds__(128) void k_mlp(const float* __restrict__ xg, const float* __restrict__ xn,
                                             const float* __restrict__ mlp_w, const float* __restrict__ mlp_b,
                                             float* __restrict__ out) {
    int b = blockIdx.x;
    int t = threadIdx.x;
    __shared__ float cat[2*HIDD];
    cat[t] = xg[b*HIDD + t];
    cat[HIDD + t] = xn[b*HIDD + t];
    __syncthreads();
    if (t < OUTD) {
        float acc = mlp_b[t];
        for (int j = 0; j < 2*HIDD; j++) acc += cat[j] * mlp_w[t*2*HIDD + j];
        out[b*OUTD + t] = acc;
    }
}

// ---------------- launcher ----------------
extern "C" void kernel_launch(void* const* d_in, const int* in_sizes, int n_in,
                              void* d_out, int out_size, void* d_ws, size_t ws_size,
                              hipStream_t stream)
{
    const float* node_emb = (const float*)d_in[0];
    const float* rel_emb  = (const float*)d_in[1];
    const float* lin_w    = (const float*)d_in[2];
    const float* lin_b    = (const float*)d_in[3];
    const float* alpha_w  = (const float*)d_in[4];
    // d_in[5] alpha_b: shift-invariant under softmax over v -> unused
    const float* beta_w   = (const float*)d_in[6];
    const float* beta_b   = (const float*)d_in[7];
    const float* wr_w     = (const float*)d_in[8];
    const float* wr_b     = (const float*)d_in[9];
    const float* conv_w   = (const float*)d_in[10];
    const float* conv_b   = (const float*)d_in[11];
    const float* mlp_w    = (const float*)d_in[12];
    const float* mlp_b    = (const float*)d_in[13];
    const float* visit    = (const float*)d_in[14];
    const float* ehr      = (const float*)d_in[15];
    const int* node_ids   = (const int*)d_in[16];
    const int* rel_ids    = (const int*)d_in[17];
    const int* ei         = (const int*)d_in[18];
    const int* batch      = (const int*)d_in[19];
    const int* esrc = ei;
    const int* edst = ei + WS_E;
    float* out = (float*)d_out;

    char* p = (char*)d_ws;
    auto take = [&](size_t bytes) -> char* {
        char* q = p;
        p += (bytes + 255) & ~(size_t)255;
        return q;
    };
    float* x      = (float*)take((size_t)WS_N*HIDD*4);             // 25.6 MB
    __bf16* xb    = (__bf16*)take((size_t)WS_N*HIDD*2);            // 12.8 MB bf16 shadow of x
    float* zbuf   = (float*)take((size_t)LL*BV*VV*NNODES*4);       // 30.7 MB (aggbuf aliases: z dead after attnpool)
    float* zbuf2  = (float*)take((size_t)LL*BV*VV*NNODES*4);       // 30.7 MB split-K partial 2
    float* aggbuf = zbuf;
    float* attn   = (float*)take((size_t)LL*BV*NNODES*4);
    float* betab  = (float*)take((size_t)LL*BV*VV*4);
    float* attnnd = (float*)take((size_t)LL*WS_N*4);
    float* Wnode  = (float*)take((size_t)NNODES*HIDD*4);
    float* Wrel   = (float*)take((size_t)NRELS*HIDD*4);
    __bf16* relmsg= (__bf16*)take((size_t)LL*NRELS*HIDD*2);
    // small accumulators zeroed with ONE memset: keep contiguous
    float* xgsum  = (float*)take((size_t)BV*HIDD*4);
    float* xnsum  = (float*)take((size_t)BV*HIDD*4);
    float* esum   = (float*)take((size_t)BV*4);
    size_t small_zero_bytes = (size_t)((char*)(esum + BV) - (char*)xgsum);
    float* xg     = (float*)take((size_t)BV*HIDD*4);
    float* xn     = (float*)take((size_t)BV*HIDD*4);
    int* deg      = (int*)take((size_t)WS_N*4);
    int* offs     = (int*)take((size_t)(WS_N+1)*4);
    int* cursor   = (int*)take((size_t)WS_N*4);
    int* ssrc     = (int*)take((size_t)WS_E*4);
    int* srel     = (int*)take((size_t)WS_E*4);
    int* bstart   = (int*)take((size_t)(BV+1)*4);
    if ((size_t)(p - (char*)d_ws) > ws_size) return;  // ws too small: leave output poisoned (visible failure)

    (void)hipMemsetAsync(deg, 0, (size_t)WS_N*4, stream);
    (void)hipMemsetAsync(xgsum, 0, small_zero_bytes, stream);

    // CSR by dst (graph is layer-invariant)
    k_count<<<dim3((WS_E+255)/256), 256, 0, stream>>>(edst, deg);
    k_scan<<<1, 1024, 0, stream>>>(deg, offs, cursor, WS_N);
    k_fill<<<dim3((WS_E+255)/256), 256, 0, stream>>>(edst, esrc, rel_ids, cursor, ssrc, srel);

    // Wnode = node_emb @ lin_w^T + lin_b ; Wrel likewise (split-bf16 => ~f32 accuracy)
    gemm_bt<1,0,1,0><<<dim3((NNODES+BM-1)/BM, 1, 1), 256, 0, stream>>>(
        node_emb, lin_w, Wnode, lin_b, nullptr, NNODES, HIDD, HIDD);
    gemm_bt<1,0,1,0><<<dim3((NRELS+BM-1)/BM, 1, 1), 256, 0, stream>>>(
        rel_emb, lin_w, Wrel, lin_b, nullptr, NRELS, HIDD, HIDD);
    k_relmsg<<<dim3(LL*NRELS), 128, 0, stream>>>(Wrel, wr_w, wr_b, relmsg);
    k_xinit<<<dim3((WS_N*32+255)/256), 256, 0, stream>>>(Wnode, node_ids, x, xb);
    k_beta<<<dim3(LL*BV*VV), 256, 0, stream>>>(visit, beta_w, beta_b, betab);

    // z[l, b*V+v, m] = visit2d @ alpha_w[l]^T  (XCD swizzle + split-K=2, partial buffers)
    gemm_alpha<<<dim3(960), 256, 0, stream>>>(visit, alpha_w, zbuf, zbuf2);

    k_attnpool<<<dim3((NNODES+255)/256, BV, LL), 256, 0, stream>>>(zbuf, zbuf2, betab, attn);
    k_attn_node<<<dim3((WS_N+255)/256, LL), 256, 0, stream>>>(attn, batch, node_ids, attnnd);

    for (int l = 0; l < LL; l++) {
        k_agg<<<dim3((WS_N+3)/4), 256, 0, stream>>>(
            x, xb, attnnd + (size_t)l*WS_N, relmsg + (size_t)l*NRELS*HIDD, offs, ssrc, srel, aggbuf);
        gemm_bt<1,1,1,1><<<dim3((WS_N+BM-1)/BM, 1, 1), 256, 0, stream>>>(
            aggbuf, conv_w + (size_t)l*HIDD*HIDD, x, conv_b + (size_t)l*HIDD, xb,
            WS_N, HIDD, HIDD);
    }

    k_bstart<<<1, 64, 0, stream>>>(batch, bstart);
    k_pool_partial<<<dim3((WS_N+127)/128), 256, 0, stream>>>(x, batch, xgsum);
    k_pool_fin<<<BV, 128, 0, stream>>>(xgsum, bstart, xg);
    k_ehrpool<<<dim3(16, BV), 128, 0, stream>>>(ehr, node_emb, xnsum, esum);
    k_xnode_fin<<<BV, 128, 0, stream>>>(xnsum, esum, lin_w, lin_b, xn);
    k_mlp<<<BV, 128, 0, stream>>>(xg, xn, mlp_w, mlp_b, out);
}